// Round 15
// baseline (5284.457 us; speedup 1.0000x reference)
//
#include <hip/hip_runtime.h>
#include <hip/hip_fp16.h>
#include <cstdint>
#include <cstddef>

// ---------------- problem constants ----------------
#define B_  2
#define S_  1024
#define D_  4096
#define KV_ 1024
#define F_  14336
#define H_  32
#define HK_ 8
#define HD_ 128
#define M_  2048   // B*S

typedef _Float16 f16;
typedef f16   f16x8 __attribute__((ext_vector_type(8)));
typedef f16   f16x4 __attribute__((ext_vector_type(4)));
typedef float f32x4 __attribute__((ext_vector_type(4)));
typedef unsigned u32x2 __attribute__((ext_vector_type(2)));
typedef unsigned u32x4 __attribute__((ext_vector_type(4)));
typedef int      i32x4 __attribute__((ext_vector_type(4)));

#define AS1(p) ((const __attribute__((address_space(1))) void*)(p))
#define AS3(p) ((__attribute__((address_space(3))) void*)(p))

__device__ __constant__ float NF4_C[16] = {
 -1.0f, -0.6961928009986877f, -0.5250730514526367f, -0.39491748809814453f,
 -0.28444138169288635f, -0.18477343022823334f, -0.09105003625154495f, 0.0f,
 0.07958029955625534f, 0.16093020141124725f, 0.24611230194568634f,
 0.33791524171829224f, 0.44070982933044434f, 0.5626170039176941f,
 0.7229568362236023f, 1.0f };

// per-layer f16 weight-cache element offsets (QKV only)
#define WC_LAYER  25165824ull      // q(16.8M) + k(4.2M) + v(4.2M) elems

// ---------------- dtype detection (u8 vs i32 idx arrays) ----------------
__global__ void k_detect(const unsigned* __restrict__ p, int* __restrict__ flag){
    if (threadIdx.x == 0){
        int u8 = 0;
        for (int i = 0; i < 256; ++i) if (p[i] >= 16u) { u8 = 1; break; }
        *flag = u8;
    }
}

// ---------------- QKV dequant: idx -> f16 cache ----------------
// grid = 2 * 12288 blocks; per-layer segments (blocks): q 8192 | k 2048 | v 2048
__global__ __launch_bounds__(256) void k_dequant_qkv(
        const void* __restrict__ qi, const void* __restrict__ ki, const void* __restrict__ vi,
        const float* __restrict__ qa, const float* __restrict__ ka, const float* __restrict__ va,
        f16* __restrict__ wc, const int* __restrict__ flag)
{
    __shared__ __half2 T[3856];
    int t = threadIdx.x;
    if (t < 256){
        int b0 = t & 15, b1 = t >> 4;
        T[b0 + (b1 << 8)] = __halves2half2(__float2half(NF4_C[b0]), __float2half(NF4_C[b1]));
    }
    __syncthreads();
    int blk = blockIdx.x;
    int l = blk / 12288; blk -= l * 12288;
    const size_t DDc = (size_t)D_ * D_, KVDc = (size_t)KV_ * D_;
    size_t oDD = (size_t)l * DDc, oKVD = (size_t)l * KVDc;
    f16* wl = wc + (size_t)l * WC_LAYER;
    const void* src; const float* am; size_t so; f16* dst;
    if (blk < 8192)       { src = qi; am = qa; so = oDD;  dst = wl; }
    else if (blk < 10240) { src = ki; am = ka; so = oKVD; dst = wl + DDc;        blk -= 8192; }
    else                  { src = vi; am = va; so = oKVD; dst = wl + DDc + KVDc; blk -= 10240; }
    size_t i = ((size_t)blk * 256 + t) * 8;
    float amv = am[(so + i) >> 6];
    __half2 am2 = __float2half2_rn(amv);
    union { __half2 h2[4]; u32x4 u4; } R;
    if (*flag){
        u32x2 u = *(const u32x2*)((const uint8_t*)src + so + i);
        R.h2[0] = __hmul2(T[u.x & 0xFFFFu], am2);
        R.h2[1] = __hmul2(T[u.x >> 16],     am2);
        R.h2[2] = __hmul2(T[u.y & 0xFFFFu], am2);
        R.h2[3] = __hmul2(T[u.y >> 16],     am2);
    } else {
        const i32x4* s4 = (const i32x4*)((const int*)src + so + i);
        i32x4 a0 = s4[0], a1 = s4[1];
        R.h2[0] = __hmul2(T[a0.x | (a0.y << 8)], am2);
        R.h2[1] = __hmul2(T[a0.z | (a0.w << 8)], am2);
        R.h2[2] = __hmul2(T[a1.x | (a1.y << 8)], am2);
        R.h2[3] = __hmul2(T[a1.z | (a1.w << 8)], am2);
    }
    *(u32x4*)(dst + i) = R.u4;
}

// ---------------- embedding gather (fp32) ----------------
__global__ __launch_bounds__(256) void k_embed(const int* __restrict__ ids,
        const float* __restrict__ E, float* __restrict__ Hh)
{
    int row = blockIdx.x, t = threadIdx.x;
    int id = ids[row];
    const float4* s4 = (const float4*)(E + (size_t)id * D_);
    float4* d4 = (float4*)(Hh + (size_t)row * D_);
    #pragma unroll
    for (int i = 0; i < 4; ++i) d4[t + 256*i] = s4[t + 256*i];
}

// ---------------- RoPE tables ----------------
__global__ __launch_bounds__(256) void k_ropetab(float* __restrict__ cosT, float* __restrict__ sinT){
    int id = blockIdx.x * 256 + threadIdx.x;
    int d = id & 63, s = id >> 6;
    float inv = powf(500000.0f, -(float)d * (1.0f/64.0f));
    float ang = (float)s * inv;
    cosT[id] = cosf(ang);
    sinT[id] = sinf(ang);
}

// ---------------- additive attention mask ----------------
__global__ void k_maskadd(const int* __restrict__ am, float* __restrict__ ma){
    int i = blockIdx.x * 256 + threadIdx.x;
    ma[i] = am[i] ? 0.f : -1e30f;
}

// ---------------- RMSNorm ----------------
template<int F16OUT>
__global__ __launch_bounds__(256) void k_rmsnorm(const float* __restrict__ X,
        const float* __restrict__ W, void* __restrict__ outv)
{
    int row = blockIdx.x, t = threadIdx.x;
    const float4* x4 = (const float4*)(X + (size_t)row * D_);
    float4 xs[4]; float ss = 0.f;
    #pragma unroll
    for (int i = 0; i < 4; ++i){
        xs[i] = x4[t + 256*i];
        ss += xs[i].x*xs[i].x + xs[i].y*xs[i].y + xs[i].z*xs[i].z + xs[i].w*xs[i].w;
    }
    for (int m = 32; m; m >>= 1) ss += __shfl_xor(ss, m, 64);
    __shared__ float red[4];
    if ((t & 63) == 0) red[t >> 6] = ss;
    __syncthreads();
    ss = red[0] + red[1] + red[2] + red[3];
    float rs = rsqrtf(ss * (1.0f / D_) + 1e-5f);
    #pragma unroll
    for (int i = 0; i < 4; ++i){
        int c0 = (t + 256*i) * 4;
        float4 wv = *(const float4*)(W + c0);
        float o0 = xs[i].x*rs*wv.x, o1 = xs[i].y*rs*wv.y;
        float o2 = xs[i].z*rs*wv.z, o3 = xs[i].w*rs*wv.w;
        if (F16OUT){
            f16x4 ov = { (f16)o0, (f16)o1, (f16)o2, (f16)o3 };
            *(f16x4*)((f16*)outv + (size_t)row * D_ + c0) = ov;
        } else {
            float4 ov = {o0, o1, o2, o3};
            *(float4*)((float*)outv + (size_t)row * D_ + c0) = ov;
        }
    }
}

// ---------------- fused split-K combine + residual + RMSNorm ----------------
template<int F16OUT>
__global__ __launch_bounds__(256) void k_combnorm(float* __restrict__ H,
        const float* __restrict__ p0, const float* __restrict__ p1,
        const float* __restrict__ W, void* __restrict__ outv)
{
    int row = blockIdx.x, t = threadIdx.x;
    size_t base = (size_t)row * D_;
    float4 xs[4]; float ss = 0.f;
    #pragma unroll
    for (int i = 0; i < 4; ++i){
        int c4 = (t + 256*i) * 4;
        float4 hv = *(const float4*)(H + base + c4);
        float4 a  = *(const float4*)(p0 + base + c4);
        float4 b  = *(const float4*)(p1 + base + c4);
        hv.x += a.x + b.x; hv.y += a.y + b.y; hv.z += a.z + b.z; hv.w += a.w + b.w;
        *(float4*)(H + base + c4) = hv;
        xs[i] = hv;
        ss += hv.x*hv.x + hv.y*hv.y + hv.z*hv.z + hv.w*hv.w;
    }
    for (int m = 32; m; m >>= 1) ss += __shfl_xor(ss, m, 64);
    __shared__ float red[4];
    if ((t & 63) == 0) red[t >> 6] = ss;
    __syncthreads();
    ss = red[0] + red[1] + red[2] + red[3];
    float rs = rsqrtf(ss * (1.0f / D_) + 1e-5f);
    #pragma unroll
    for (int i = 0; i < 4; ++i){
        int c0 = (t + 256*i) * 4;
        float4 wv = *(const float4*)(W + c0);
        float o0 = xs[i].x*rs*wv.x, o1 = xs[i].y*rs*wv.y;
        float o2 = xs[i].z*rs*wv.z, o3 = xs[i].w*rs*wv.w;
        if (F16OUT){
            f16x4 ov = { (f16)o0, (f16)o1, (f16)o2, (f16)o3 };
            *(f16x4*)((f16*)outv + base + c0) = ov;
        } else {
            float4 ov = {o0, o1, o2, o3};
            *(float4*)((float*)outv + base + c0) = ov;
        }
    }
}

// ---------------- merged QKV post-proc: rope(q), rope(k), vtrans(v) ----------------
__global__ __launch_bounds__(256) void k_qkvprep(const f16* __restrict__ qkv,
        f16* __restrict__ qr, f16* __restrict__ kr, f16* __restrict__ vtr,
        const float* __restrict__ cosT, const float* __restrict__ sinT)
{
    const int istr = D_ + 2 * KV_;
    int blk = blockIdx.x;
    if (blk < 16384){
        int p = blk * 256 + threadIdx.x;
        int d = p & 63;
        int h = (p >> 6) & 31;
        int s = (p >> 11) & (S_ - 1);
        int b = p >> 21;
        size_t ib = (size_t)(b * S_ + s) * istr + (size_t)h * HD_;
        float x1 = (float)qkv[ib + d], x2 = (float)qkv[ib + 64 + d];
        float c = cosT[s*64 + d], sn = sinT[s*64 + d];
        size_t ob = (((size_t)((b << 5) + h)) * S_ + (size_t)s) * HD_;
        qr[ob + d]      = (f16)(x1 * c - x2 * sn);
        qr[ob + 64 + d] = (f16)(x2 * c + x1 * sn);
    } else if (blk < 20480){
        int p = (blk - 16384) * 256 + threadIdx.x;
        int d = p & 63;
        int h = (p >> 6) & 7;
        int s = (p >> 9) & (S_ - 1);
        int b = p >> 19;
        size_t ib = (size_t)(b * S_ + s) * istr + (size_t)(D_) + (size_t)h * HD_;
        float x1 = (float)qkv[ib + d], x2 = (float)qkv[ib + 64 + d];
        float c = cosT[s*64 + d], sn = sinT[s*64 + d];
        size_t ob = (((size_t)((b << 3) + h)) * S_ + (size_t)s) * HD_;
        kr[ob + d]      = (f16)(x1 * c - x2 * sn);
        kr[ob + 64 + d] = (f16)(x2 * c + x1 * sn);
    } else {
        int p = (blk - 20480) * 256 + threadIdx.x;
        int s  = p & (S_ - 1);
        int d  = (p >> 10) & (HD_ - 1);
        int hk = (p >> 17) & (HK_ - 1);
        int b  = p >> 20;
        f16 v = qkv[(size_t)(b * S_ + s) * istr + (size_t)(D_ + KV_) + (size_t)hk * HD_ + d];
        vtr[(((size_t)(b * HK_ + hk)) * HD_ + d) * S_ + s] = v;
    }
}

// ---------------- fused flash attention ----------------
__global__ __launch_bounds__(256) void k_flash(const f16* __restrict__ Qr, const f16* __restrict__ Kr,
        const f16* __restrict__ Vt, const float* __restrict__ mAddG, f16* __restrict__ ctx)
{
    __shared__ f16 KS[8192];
    __shared__ f16 VS[8192];
    __shared__ f16 PS[8192];
    const int t = threadIdx.x;
    const int w = t >> 6, l = t & 63;
    const int lr = l & 15, lg = l >> 4;
    const int qt = blockIdx.x, bh = blockIdx.y;
    const int b = bh >> 5, hh = bh & 31, hk = hh >> 2;
    const f16* Qb = Qr + ((size_t)bh * S_ + (size_t)qt*128) * HD_;
    const f16* Kb = Kr + (size_t)(b * HK_ + hk) * S_ * HD_;
    const f16* Vb = Vt + (size_t)(b * HK_ + hk) * HD_ * S_;

    auto stage16x128 = [&](const f16* src, int lds_, f16* dst){
        int rowl = t >> 4;
        int cs = ((t & 15) ^ (rowl & 7)) << 3;
        #pragma unroll
        for (int g = 0; g < 4; ++g)
            __builtin_amdgcn_global_load_lds(AS1(src + (size_t)(g*16 + rowl)*lds_ + cs),
                AS3(dst + g*2048 + w*512), 16, 0, 0);
    };
    auto stage32x64 = [&](const f16* src, int lds_, f16* dst){
        int rowl = t >> 3;
        int cs = ((t & 7) ^ (rowl & 7)) << 3;
        #pragma unroll
        for (int g = 0; g < 4; ++g)
            __builtin_amdgcn_global_load_lds(AS1(src + (size_t)(g*32 + rowl)*lds_ + cs),
                AS3(dst + g*2048 + w*512), 16, 0, 0);
    };

    stage16x128(Qb, HD_, KS);
    stage16x128(Qb + 64*HD_, HD_, VS);
    __syncthreads();
    f16x8 qF[2][4];
    {
        const f16* qsrc = (w < 2) ? KS : VS;
        int rbase = (w & 1) * 32;
        #pragma unroll
        for (int m = 0; m < 2; ++m)
            #pragma unroll
            for (int kd = 0; kd < 4; ++kd){
                int row = rbase + m*16 + lr;
                qF[m][kd] = *(const f16x8*)&qsrc[row*128 + (((kd*4 + lg) ^ (row & 7)) << 3)];
            }
    }
    __syncthreads();

    float mrow[2][4], lrow[2][4];
    f32x4 oacc[2][8];
    #pragma unroll
    for (int m = 0; m < 2; ++m)
        #pragma unroll
        for (int r = 0; r < 4; ++r){ mrow[m][r] = -1e30f; lrow[m][r] = 0.f; }
    #pragma unroll
    for (int m = 0; m < 2; ++m)
        #pragma unroll
        for (int dn = 0; dn < 8; ++dn){ f32x4 z = {0,0,0,0}; oacc[m][dn] = z; }

    const float ISQ = 0.08838834764831845f;
    const int ktMax = 2*qt + 1;

    for (int kt = 0; kt <= ktMax; ++kt){
        stage16x128(Kb + (size_t)(kt*64)*HD_, HD_, KS);
        __syncthreads();

        f32x4 sacc[2][4];
        #pragma unroll
        for (int m = 0; m < 2; ++m)
            #pragma unroll
            for (int n = 0; n < 4; ++n){ f32x4 z = {0,0,0,0}; sacc[m][n] = z; }
        #pragma unroll
        for (int n = 0; n < 4; ++n){
            int krow = n*16 + lr;
            #pragma unroll
            for (int kd = 0; kd < 4; ++kd){
                f16x8 kF = *(const f16x8*)&KS[krow*128 + (((kd*4 + lg) ^ (krow & 7)) << 3)];
                #pragma unroll
                for (int m = 0; m < 2; ++m)
                    sacc[m][n] = __builtin_amdgcn_mfma_f32_16x16x32_f16(qF[m][kd], kF, sacc[m][n], 0, 0, 0);
            }
        }

        stage32x64(Vb + kt*64, S_, VS);

        float mAdd[4];
        #pragma unroll
        for (int n = 0; n < 4; ++n) mAdd[n] = mAddG[b*S_ + kt*64 + n*16 + lr];
        int diag = (kt >= 2*qt);
        #pragma unroll
        for (int m = 0; m < 2; ++m)
        #pragma unroll
        for (int n = 0; n < 4; ++n)
        #pragma unroll
        for (int r = 0; r < 4; ++r){
            float s = sacc[m][n][r] * ISQ + mAdd[n];
            if (diag && (kt*64 + n*16 + lr) > (qt*128 + w*32 + m*16 + lg*4 + r)) s = -1e30f;
            sacc[m][n][r] = s;
        }
        #pragma unroll
        for (int m = 0; m < 2; ++m)
        #pragma unroll
        for (int r = 0; r < 4; ++r){
            float tm = fmaxf(fmaxf(sacc[m][0][r], sacc[m][1][r]), fmaxf(sacc[m][2][r], sacc[m][3][r]));
            #pragma unroll
            for (int msk = 1; msk < 16; msk <<= 1) tm = fmaxf(tm, __shfl_xor(tm, msk, 64));
            float mn = fmaxf(mrow[m][r], tm);
            float scl = __expf(mrow[m][r] - mn);
            mrow[m][r] = mn;
            float rs = 0.f;
            #pragma unroll
            for (int n = 0; n < 4; ++n){
                float p = __expf(sacc[m][n][r] - mn);
                sacc[m][n][r] = p; rs += p;
            }
            #pragma unroll
            for (int msk = 1; msk < 16; msk <<= 1) rs += __shfl_xor(rs, msk, 64);
            lrow[m][r] = lrow[m][r] * scl + rs;
            #pragma unroll
            for (int dn = 0; dn < 8; ++dn) oacc[m][dn][r] *= scl;
        }
        #pragma unroll
        for (int m = 0; m < 2; ++m)
        #pragma unroll
        for (int n = 0; n < 4; ++n)
        #pragma unroll
        for (int r = 0; r < 4; ++r){
            int rowl = m*16 + lg*4 + r;
            int slot = (n*2 + (lr >> 3)) ^ (rowl & 7);
            PS[w*2048 + rowl*64 + slot*8 + (lr & 7)] = (f16)sacc[m][n][r];
        }
        __syncthreads();

        f16x8 pF[2][2];
        #pragma unroll
        for (int m = 0; m < 2; ++m)
            #pragma unroll
            for (int kd = 0; kd < 2; ++kd){
                int prow = m*16 + lr;
                pF[m][kd] = *(const f16x8*)&PS[w*2048 + prow*64 + (((kd*4 + lg) ^ (prow & 7)) << 3)];
            }
        #pragma unroll
        for (int dn = 0; dn < 8; ++dn){
            int vrow = dn*16 + lr;
            #pragma unroll
            for (int kd = 0; kd < 2; ++kd){
                f16x8 vF = *(const f16x8*)&VS[vrow*64 + (((kd*4 + lg) ^ (vrow & 7)) << 3)];
                #pragma unroll
                for (int m = 0; m < 2; ++m)
                    oacc[m][dn] = __builtin_amdgcn_mfma_f32_16x16x32_f16(pF[m][kd], vF, oacc[m][dn], 0, 0, 0);
            }
        }
        __syncthreads();
    }

    #pragma unroll
    for (int m = 0; m < 2; ++m)
    #pragma unroll
    for (int dn = 0; dn < 8; ++dn)
    #pragma unroll
    for (int r = 0; r < 4; ++r){
        int grow = qt*128 + w*32 + m*16 + lg*4 + r;
        int gcol = hh*128 + dn*16 + lr;
        float v = oacc[m][dn][r] / fmaxf(lrow[m][r], 1e-30f);
        ctx[((size_t)(b * S_) + grow) * D_ + gcol] = (f16)v;
    }
}

// ---------------- 256x256 8-phase pipelined GEMM, f16 B (QKV only) ----------------
template<int OUT>
__global__ __launch_bounds__(512, 1) void k_gemm3(const f16* __restrict__ A, const f16* __restrict__ Bp,
        void* __restrict__ Cv, const f16* __restrict__ G, int Kd, int ldk, int ldc)
{
    __shared__ f16 LDS[65536];
    const int t = threadIdx.x;
    const int w = t >> 6, l = t & 63;
    const int wm = w >> 2, wn = w & 3;

    int gx = gridDim.x, gy = gridDim.y;
    int nWG = gx * gy * gridDim.z;
    int n = (blockIdx.z * gy + blockIdx.y) * gx + blockIdx.x;
    int q = nWG >> 3;
    int sw = (n & 7) * q + (n >> 3);
    int by = sw % gy; int r1 = sw / gy; int bx = r1 % gx; int bz = r1 / gx;

    const int row0 = by * 256, col0 = bx * 256;
    const size_t koff = (size_t)bz * Kd;
    const int NT = Kd >> 6;

    const int swzk = ((t & 7) ^ ((t >> 3) & 7)) * 8;
    const f16* pA[2]; const f16* pB[2];
    #pragma unroll
    for (int l2 = 0; l2 < 2; ++l2){
        pA[l2] = A  + (size_t)(row0 + l2*128 + (t >> 3)) * ldk + koff + swzk;
        int wnc = (l2*64 + (t >> 3)) >> 5;
        pB[l2] = Bp + (size_t)(col0 + wnc*64 + ((t >> 3) & 31)) * ldk + koff + swzk;
    }

    auto stA = [&](int g, int tt, int buf){
        size_t so = (size_t)tt * 64;
        #pragma unroll
        for (int l2 = 0; l2 < 2; ++l2)
            __builtin_amdgcn_global_load_lds(AS1(pA[l2] + (size_t)g*64*ldk + so),
                AS3(&LDS[buf*16384 + g*8192 + l2*4096 + w*512]), 16, 0, 0);
    };
    auto stB = [&](int g, int tt, int buf){
        size_t so = (size_t)tt * 64;
        #pragma unroll
        for (int l2 = 0; l2 < 2; ++l2)
            __builtin_amdgcn_global_load_lds(AS1(pB[l2] + (size_t)g*32*ldk + so),
                AS3(&LDS[32768 + buf*16384 + g*8192 + l2*4096 + w*512]), 16, 0, 0);
    };

    const int lrow = (l & 15) * 64;
    const int kp0 = (((l >> 4))     ^ (l & 7)) * 8;
    const int kp1 = ((4 + (l >> 4)) ^ (l & 7)) * 8;

    f16x8 aR[2][4], bR0[2][2], bR1[2][2];
    auto rdA = [&](int g, int buf){
        int base = buf*16384 + g*8192 + wm*4096 + lrow;
        #pragma unroll
        for (int mf = 0; mf < 4; ++mf){
            aR[0][mf] = *(const f16x8*)&LDS[base + mf*1024 + kp0];
            aR[1][mf] = *(const f16x8*)&LDS[base + mf*1024 + kp1];
        }
    };
    auto rdB = [&](int g, int buf, f16x8 (&bR)[2][2]){
        int base = 32768 + buf*16384 + g*8192 + wn*2048 + lrow;
        #pragma unroll
        for (int nf = 0; nf < 2; ++nf){
            bR[0][nf] = *(const f16x8*)&LDS[base + nf*1024 + kp0];
            bR[1][nf] = *(const f16x8*)&LDS[base + nf*1024 + kp1];
        }
    };

    f32x4 zero = {0.f, 0.f, 0.f, 0.f};
    f32x4 acc[8][4];
    #pragma unroll
    for (int mi = 0; mi < 8; ++mi)
        #pragma unroll
        for (int ni = 0; ni < 4; ++ni) acc[mi][ni] = zero;

    #define MMQ(qm, qn, bR) { \
        __builtin_amdgcn_s_setprio(1); \
        _Pragma("unroll") \
        for (int ks = 0; ks < 2; ++ks) \
            _Pragma("unroll") \
            for (int mf = 0; mf < 4; ++mf) \
                _Pragma("unroll") \
                for (int nf = 0; nf < 2; ++nf) \
                    acc[(qm)*4+mf][(qn)*2+nf] = __builtin_amdgcn_mfma_f32_16x16x32_f16(aR[ks][mf], bR[ks][nf], acc[(qm)*4+mf][(qn)*2+nf], 0, 0, 0); \
        __builtin_amdgcn_s_setprio(0); }
    #define LGKM0 { asm volatile("s_waitcnt lgkmcnt(0)" ::: "memory"); __builtin_amdgcn_sched_barrier(0); }
    #define VM4   { asm volatile("s_waitcnt vmcnt(4)" ::: "memory"); }
    #define BAR   __builtin_amdgcn_s_barrier()

    stA(0, 0, 0); stB(1, 0, 0); stA(1, 0, 0); stB(0, 0, 0);
    if (NT > 1){ stA(0, 1, 1); stB(1, 1, 1); }
    VM4; BAR;

    for (int tt = 0; tt < NT; tt += 2){
        int c2 = (tt + 2 < NT) ? tt + 2 : NT - 1;
        int c3 = (tt + 3 < NT) ? tt + 3 : NT - 1;
        rdA(0, 0); rdB(0, 0, bR0);
        stA(1, tt+1 < NT ? tt+1 : NT-1, 1); stB(0, tt+1 < NT ? tt+1 : NT-1, 1);
        BAR; LGKM0; MMQ(0, 0, bR0); BAR;
        rdB(1, 0, bR1);
        BAR; LGKM0; MMQ(0, 1, bR1); BAR;
        rdA(1, 0);
        stA(0, c2, 0);
        BAR; LGKM0; MMQ(1, 1, bR1); BAR;
        stB(1, c2, 0);
        BAR; MMQ(1, 0, bR0); VM4; BAR;
        rdA(0, 1); rdB(0, 1, bR0);
        stA(1, c2, 0); stB(0, c2, 0);
        BAR; LGKM0; MMQ(0, 0, bR0); BAR;
        rdB(1, 1, bR1);
        BAR; LGKM0; MMQ(0, 1, bR1); BAR;
        rdA(1, 1);
        stA(0, c3, 1);
        BAR; LGKM0; MMQ(1, 1, bR1); BAR;
        stB(1, c3, 1);
        BAR; MMQ(1, 0, bR0); VM4; BAR;
    }

    #pragma unroll
    for (int mi = 0; mi < 8; ++mi)
    #pragma unroll
    for (int ni = 0; ni < 4; ++ni)
    #pragma unroll
    for (int r = 0; r < 4; ++r){
        int row = row0 + wm*128 + mi*16 + ((l >> 4) << 2) + r;
        int col = col0 + wn*64  + ni*16 + (l & 15);
        float v = acc[mi][ni][r];
        if (OUT == 0){
            ((float*)Cv)[(size_t)bz * ((size_t)M_ * ldc) + (size_t)row * ldc + col] = v;
        } else if (OUT == 2){
            ((f16*)Cv)[(size_t)row * ldc + col] = (f16)v;
        } else {
            size_t idx = (size_t)row * ldc + col;
            float g = (float)G[idx];
            float sg = g / (1.f + __expf(-g));
            ((f16*)Cv)[idx] = (f16)(sg * v);
        }
    }
    #undef MMQ
    #undef LGKM0
    #undef VM4
    #undef BAR
}

// ---------------- gemm5v2: fused NF4 B-decode with BANK-SPREAD LUT ----------------
// 16 LUT replicas at stride 257 entries -> bank = ((lane&15)+byte)&31, ~4-way max.
// T14 pipeline identical to R14 (HW-validated schedule).
template<int OUT>
__global__ __launch_bounds__(512, 1) void k_gemm5(const f16* __restrict__ A, const void* __restrict__ Bi,
        size_t elemOff, const float* __restrict__ Ba, const int* __restrict__ flagp,
        void* __restrict__ Cv, const f16* __restrict__ G, int Kd, int ldk, int ldc)
{
    __shared__ f16 LDS[65536];
    __shared__ __half2 LUT[16 * 257];      // 16 bank-spread replicas
    const int t = threadIdx.x;
    const int w = t >> 6, l = t & 63;
    const int wm = w >> 2, wn = w & 3;

    #pragma unroll
    for (int e = 0; e < 8; ++e){
        int idx = t + e * 512;             // 4096 entries
        int cp = idx >> 8, by = idx & 255;
        LUT[cp * 257 + by] = __halves2half2(__float2half(NF4_C[by & 15]), __float2half(NF4_C[by >> 4]));
    }
    const int isU8 = *flagp;
    const int lco = (l & 15) * 257;        // this lane's replica base

    int gx = gridDim.x, gy = gridDim.y;
    int nWG = gx * gy * gridDim.z;
    int n = (blockIdx.z * gy + blockIdx.y) * gx + blockIdx.x;
    int q = nWG >> 3;
    int sw = (n & 7) * q + (n >> 3);
    int by0 = sw % gy; int r1 = sw / gy; int bx = r1 % gx; int bz = r1 / gx;

    const int row0 = by0 * 256, col0 = bx * 256;
    const size_t koff = (size_t)bz * Kd;
    const int NT = Kd >> 6;
    const int kb = ldk >> 6;

    const int swzk = ((t & 7) ^ ((t >> 3) & 7)) * 8;
    const f16* pA[2];
    size_t eBs[2], aBs[2];
    #pragma unroll
    for (int l2 = 0; l2 < 2; ++l2){
        pA[l2] = A  + (size_t)(row0 + l2*128 + (t >> 3)) * ldk + koff + swzk;
        int wnc = (l2*64 + (t >> 3)) >> 5;
        int rowB = col0 + wnc*64 + ((t >> 3) & 31);
        eBs[l2] = elemOff + (size_t)rowB * ldk + koff + swzk;
        aBs[l2] = ((size_t)rowB * ldk + koff) >> 6;
    }
    const uint8_t* Bu8 = (const uint8_t*)Bi;
    const int*     Bi32 = (const int*)Bi;

    auto stA = [&](int g, int tt, int buf){
        size_t so = (size_t)tt * 64;
        #pragma unroll
        for (int l2 = 0; l2 < 2; ++l2)
            __builtin_amdgcn_global_load_lds(AS1(pA[l2] + (size_t)g*64*ldk + so),
                AS3(&LDS[buf*16384 + g*8192 + l2*4096 + w*512]), 16, 0, 0);
    };

    struct BSet { u32x2 iv0, iv1; float am0, am1; };
    auto ldB = [&](int g, int T, BSet &S){
        S.iv0 = *(const u32x2*)(Bu8 + eBs[0] + (size_t)g*32*ldk + (size_t)T*64);
        S.am0 = Ba[aBs[0] + (size_t)g*32*kb + T];
        S.iv1 = *(const u32x2*)(Bu8 + eBs[1] + (size_t)g*32*ldk + (size_t)T*64);
        S.am1 = Ba[aBs[1] + (size_t)g*32*kb + T];
    };
    auto wrB = [&](int g, int T, int buf, BSet &S){
        #pragma unroll
        for (int l2 = 0; l2 < 2; ++l2){
            union { __half2 h2[4]; f16x8 v; } R;
            if (isU8){
                u32x2 u = l2 ? S.iv1 : S.iv0;
                __half2 am2 = __float2half2_rn(l2 ? S.am1 : S.am0);
                unsigned x0 = u.x & 0xFFu,          x1 = (u.x >> 8) & 0xFFu;
                unsigned x2 = (u.x >> 16) & 0xFFu,  x3 = u.x >> 24;
                unsigned y0 = u.y & 0xFFu,          y1 = (u.y >> 8) & 0xFFu;
                unsigned y2 = (u.y >> 16) & 0xFFu,  y3 = u.y >> 24;
                R.h2[0] = __hmul2(LUT[lco + (x0 | (x1 << 4)) % 256], am2);
                R.h2[1] = __hmul2(LUT[lco + (x2 | (x3 << 4)) % 256], am2);
                R.h2[2] = __hmul2(LUT[lco + (y0 | (y1 << 4)) % 256], am2);
                R.h2[3] = __hmul2(LUT[lco + (y2 | (y3 << 4)) % 256], am2);
            } else {
                size_t eoff = eBs[l2] + (size_t)g*32*ldk + (size_t)T*64;
                float amv = Ba[aBs[l2] + (size_t)g*32*kb + T];
                __half2 am2 = __float2half2_rn(amv);
                i32x4 a0 = *(const i32x4*)(Bi32 + eoff);
                i32x4 a1 = *(const i32x4*)(Bi32 + eoff + 4);
                R.h2[0] = __hmul2(LUT[lco + (a0.x | (a0.y << 4))], am2);
                R.h2[1] = __hmul2(LUT[lco + (a0.z | (a0.w << 4))], am2);
                R.h2[2] = __hmul2(LUT[lco + (a1.x | (a1.y << 4))], am2);
                R.h2[3] = __hmul2(LUT[lco + (a1.z | (a1.w << 4))], am2);
            }
            *(f16x8*)&LDS[32768 + buf*16384 + g*8192 + l2*4096 + w*512 + l*8] = R.v;
        }
    };

    const int lrow = (l & 15) * 64;
    const int kp0 = (((l >> 4))     ^ (l & 7)) * 8;
    const int kp1 = ((4 + (l >> 4)) ^ (l & 7)) * 8;

    f16x8 aR[2][4], bR0[2][2], bR1[2][2];
    auto rdA = [&](int g, int buf){
        int base = buf*16384 + g*8192 + wm*4096 + lrow;
        #pragma unroll
        for (int mf = 0; mf < 4; ++mf){
            aR[0][mf] = *(const f16x8*)&LDS[base + mf*1024 + kp0];
            aR[1][mf] = *(const f16x8*)&LDS[base + mf*1024 + kp1];
        }
    };
    auto rdB = [&](int g, int buf, f16x8 (&bR)[2][2]){
        int base = 32768 + buf*16384 + g*8192 + wn*2048 + lrow;
        #pragma unroll
        for (int nf = 0; nf < 2; ++nf){
            bR[0][nf] = *(const f16x8*)&LDS[base + nf*1024 + kp0];
            bR[1][nf] = *(const f16x8*)&LDS[base + nf*1024 + kp1];
        }
    };

    f32x4 zero = {0.f, 0.f, 0.f, 0.f};
    f32x4 acc[8][4];
    #pragma unroll
    for (int mi = 0; mi < 8; ++mi)
        #pragma unroll
        for (int ni = 0; ni < 4; ++ni) acc[mi][ni] = zero;

    #define MMQ(qm, qn, bR) { \
        __builtin_amdgcn_s_setprio(1); \
        _Pragma("unroll") \
        for (int ks = 0; ks < 2; ++ks) \
            _Pragma("unroll") \
            for (int mf = 0; mf < 4; ++mf) \
                _Pragma("unroll") \
                for (int nf = 0; nf < 2; ++nf) \
                    acc[(qm)*4+mf][(qn)*2+nf] = __builtin_amdgcn_mfma_f32_16x16x32_f16(aR[ks][mf], bR[ks][nf], acc[(qm)*4+mf][(qn)*2+nf], 0, 0, 0); \
        __builtin_amdgcn_s_setprio(0); }
    #define LGKM0 { asm volatile("s_waitcnt lgkmcnt(0)" ::: "memory"); __builtin_amdgcn_sched_barrier(0); }
    #define VM6   { asm volatile("s_waitcnt vmcnt(6)" ::: "memory"); }
    #define BAR   __builtin_amdgcn_s_barrier()

    __syncthreads();                       // LUT visible
    BSet S4, S5, S8, SW1, Sa, Sb, Sc;
    stA(0, 0, 0); stA(1, 0, 0); stA(0, 1, 1);
    ldB(1, 0, Sa); ldB(0, 0, Sb); ldB(1, 1, Sc); ldB(0, 1, SW1);
    wrB(1, 0, 0, Sa); wrB(0, 0, 0, Sb); wrB(1, 1, 1, Sc);
    VM6; LGKM0; BAR;

    for (int tt = 0; tt < NT; tt += 2){
        int n1 = (tt + 1 < NT) ? tt + 1 : NT - 1;
        int c2 = (tt + 2 < NT) ? tt + 2 : NT - 1;
        int c3 = (tt + 3 < NT) ? tt + 3 : NT - 1;
        // ph1
        rdA(0, 0); rdB(0, 0, bR0);
        stA(1, n1, 1);
        wrB(0, n1, 1, SW1);
        ldB(1, c2, S4);
        BAR; LGKM0; MMQ(0, 0, bR0); BAR;
        // ph2
        rdB(1, 0, bR1);
        ldB(0, c2, S5);
        BAR; LGKM0; MMQ(0, 1, bR1); BAR;
        // ph3
        rdA(1, 0);
        stA(0, c2, 0);
        BAR; LGKM0; MMQ(1, 1, bR1); BAR;
        // ph4
        wrB(1, c2, 0, S4);
        BAR; MMQ(1, 0, bR0); VM6; BAR;
        // ph5
        rdA(0, 1); rdB(0, 1, bR0);
        stA(1, c2, 0);
        wrB(0, c2, 0, S5);
        ldB(1, c3, S8);
        BAR; LGKM0; MMQ(0, 0, bR0); BAR;
        // ph6
        rdB(1, 1, bR1);
        ldB(0, c3, SW1);
        BAR; LGKM0; MMQ(0, 1, bR1); BAR;
        // ph7
        rdA(1, 1);
        stA(0, c3, 1);
        BAR; LGKM0; MMQ(1, 1, bR1); BAR;
        // ph8
        wrB(1, c3, 1, S8);
        BAR; MMQ(1, 0, bR0); VM6; BAR;
    }

    #pragma unroll
    for (int mi = 0; mi < 8; ++mi)
    #pragma unroll
    for (int ni = 0; ni < 4; ++ni)
    #pragma unroll
    for (int r = 0; r < 4; ++r){
        int row = row0 + wm*128 + mi*16 + ((l >> 4) << 2) + r;
        int col = col0 + wn*64  + ni*16 + (l & 15);
        float v = acc[mi][ni][r];
        if (OUT == 0){
            ((float*)Cv)[(size_t)bz * ((size_t)M_ * ldc) + (size_t)row * ldc + col] = v;
        } else if (OUT == 2){
            ((f16*)Cv)[(size_t)row * ldc + col] = (f16)v;
        } else {
            size_t idx = (size_t)row * ldc + col;
            float g = (float)G[idx];
            float sg = g / (1.f + __expf(-g));
            ((f16*)Cv)[idx] = (f16)(sg * v);
        }
    }
    #undef MMQ
    #undef LGKM0
    #undef VM6
    #undef BAR
}

// ---------------- masked mean pool, 2-stage ----------------
__global__ __launch_bounds__(256) void k_pool1(const float* __restrict__ Hn, const int* __restrict__ amask,
        float* __restrict__ part, float* __restrict__ cntp)
{
    int d0 = blockIdx.x * 256 + threadIdx.x;
    int b  = blockIdx.y;
    int z  = blockIdx.z;
    int s0 = z * 128;
    float s = 0.f;
    for (int i = 0; i < 128; ++i){
        int row = s0 + i;
        if (amask[b * S_ + row])
            s += Hn[((size_t)(b * S_ + row)) * D_ + d0];
    }
    part[((size_t)(z * B_ + b)) * D_ + d0] = s;
    if (blockIdx.x == 0 && threadIdx.x == 0){
        float c = 0.f;
        for (int i = 0; i < 128; ++i) c += (amask[b * S_ + s0 + i] != 0) ? 1.f : 0.f;
        cntp[z * B_ + b] = c;
    }
}
__global__ __launch_bounds__(256) void k_pool2(const float* __restrict__ part, const float* __restrict__ cntp,
        float* __restrict__ outp)
{
    int gid = blockIdx.x * 256 + threadIdx.x;
    int b = gid >> 12, d = gid & (D_ - 1);
    float s = 0.f, c = 0.f;
    #pragma unroll
    for (int z = 0; z < 8; ++z){
        s += part[((size_t)(z * B_ + b)) * D_ + d];
        c += cntp[z * B_ + b];
    }
    outp[gid] = s / fmaxf(c, 1e-9f);
}

// ---------------- launch ----------------
extern "C" void kernel_launch(void* const* d_in, const int* in_sizes, int n_in,
                              void* d_out, int out_size, void* d_ws, size_t ws_size,
                              hipStream_t stream)
{
    (void)in_sizes; (void)n_in; (void)out_size; (void)ws_size;
    const int*   ids   = (const int*)  d_in[0];
    const int*   amask = (const int*)  d_in[1];
    const float* embed = (const float*)d_in[2];
    const void*  qi = d_in[3];  const float* qa = (const float*)d_in[4];
    const void*  ki = d_in[5];  const float* ka = (const float*)d_in[6];
    const void*  vi = d_in[7];  const float* va = (const float*)d_in[8];
    const void*  oi = d_in[9];  const float* oa = (const float*)d_in[10];
    const void*  gi = d_in[11]; const float* ga = (const float*)d_in[12];
    const void*  ui = d_in[13]; const float* ua = (const float*)d_in[14];
    const void*  di = d_in[15]; const float* da = (const float*)d_in[16];
    const float* ln1 = (const float*)d_in[17];
    const float* ln2 = (const float*)d_in[18];
    const float* lnf = (const float*)d_in[19];

    const size_t DD  = (size_t)D_ * D_;
    const size_t FD  = (size_t)F_ * D_;

    char* ws = (char*)d_ws;
    int*   flag = (int*)ws;
    float* h    = (float*)(ws + 256);
    float* cosT = (float*)(ws + 256 + 33554432);
    float* sinT = cosT + 65536;
    f16*   xin  = (f16*)(ws + 34078976);
    char*  R4   = ws + 168296704;
    f16* qkv16 = (f16*)(R4);
    f16* qr  = (f16*)(R4 + 25165824);
    f16* kr  = (f16*)(R4 + 41943040);
    f16* vtr = (f16*)(R4 + 46137344);
    f16* ctx = (f16*)(R4 + 50331648);
    char* R5 = R4 + 67108864;
    f16*    gbuf   = (f16*)R5;
    float*  pR5_0  = (float*)R5;
    float*  pR5_1  = (float*)(R5 + 33554432);
    float*  pR4_0  = (float*)R4;
    float*  pR4_1  = (float*)(R4 + 33554432);
    float*  hn     = (float*)R4;
    float*  part   = (float*)R5;
    float*  cntp   = (float*)(R5 + 1048576);
    float*  maskAdd= (float*)(ws + 310378496);
    f16*    wc     = (f16*)(ws + 335544320);   // QKV f16 cache (both layers, 100 MB)

    const int QKV_N = D_ + 2 * KV_;

    k_detect <<<1, 64, 0, stream>>>((const unsigned*)qi, flag);
    k_dequant_qkv<<<2*12288, 256, 0, stream>>>(qi, ki, vi, qa, ka, va, wc, flag);
    k_embed  <<<M_, 256, 0, stream>>>(ids, embed, h);
    k_ropetab<<<256, 256, 0, stream>>>(cosT, sinT);
    k_maskadd<<<(B_*S_)/256, 256, 0, stream>>>(amask, maskAdd);
    k_rmsnorm<1><<<M_, 256, 0, stream>>>(h, ln1, xin);      // layer-0 input norm

    for (int l = 0; l < 2; ++l){
        size_t oDD = (size_t)l * DD, oFD = (size_t)l * FD;
        f16* wcl = wc + (size_t)l * WC_LAYER;

        // QKV projection from f16 cache
        k_gemm3<2><<<dim3(QKV_N/256, M_/256, 1), 512, 0, stream>>>(xin, wcl, qkv16, nullptr, D_, D_, QKV_N);
        k_qkvprep<<<28672, 256, 0, stream>>>(qkv16, qr, kr, vtr, cosT, sinT);

        // fused flash attention
        k_flash<<<dim3(S_/128, B_*H_), 256, 0, stream>>>(qr, kr, vtr, maskAdd, ctx);

        // O projection: fused-dequant GEMM (split-K x2) + residual + ln2 norm
        k_gemm5<0><<<dim3(D_/256, M_/256, 2), 512, 0, stream>>>(ctx, oi, oDD, oa + oDD/64, flag,
            pR5_0, nullptr, D_/2, D_, D_);
        k_combnorm<1><<<M_, 256, 0, stream>>>(h, pR5_0, pR5_1, ln2 + l * D_, xin);

        // MLP: fused-dequant GEMMs
        k_gemm5<2><<<dim3(F_/256, M_/256, 1), 512, 0, stream>>>(xin, gi, oFD, ga + oFD/64, flag,
            gbuf, nullptr, D_, D_, F_);
        k_gemm5<3><<<dim3(F_/256, M_/256, 1), 512, 0, stream>>>(xin, ui, oFD, ua + oFD/64, flag,
            gbuf, gbuf, D_, D_, F_);
        k_gemm5<0><<<dim3(D_/256, M_/256, 2), 512, 0, stream>>>(gbuf, di, oFD, da + oFD/64, flag,
            pR4_0, nullptr, F_/2, F_, D_);

        // down combine + residual + next-input norm
        if (l == 0)
            k_combnorm<1><<<M_, 256, 0, stream>>>(h, pR4_0, pR4_1, ln1 + D_, xin);
        else
            k_combnorm<0><<<M_, 256, 0, stream>>>(h, pR4_0, pR4_1, lnf, hn);
    }

    k_pool1<<<dim3(D_/256, B_, 8), 256, 0, stream>>>(hn, amask, part, cntp);
    k_pool2<<<(B_*D_)/256, 256, 0, stream>>>(part, cntp, (float*)d_out);
}

// Round 16
// 2438.096 us; speedup vs baseline: 2.1675x; 2.1675x over previous
//
#include <hip/hip_runtime.h>
#include <hip/hip_fp16.h>
#include <cstdint>
#include <cstddef>

// ---------------- problem constants ----------------
#define B_  2
#define S_  1024
#define D_  4096
#define KV_ 1024
#define F_  14336
#define H_  32
#define HK_ 8
#define HD_ 128
#define M_  2048   // B*S

typedef _Float16 f16;
typedef f16   f16x8 __attribute__((ext_vector_type(8)));
typedef f16   f16x4 __attribute__((ext_vector_type(4)));
typedef float f32x4 __attribute__((ext_vector_type(4)));
typedef unsigned u32x2 __attribute__((ext_vector_type(2)));
typedef unsigned u32x4 __attribute__((ext_vector_type(4)));
typedef int      i32x4 __attribute__((ext_vector_type(4)));

#define AS1(p) ((const __attribute__((address_space(1))) void*)(p))
#define AS3(p) ((__attribute__((address_space(3))) void*)(p))

__device__ __constant__ float NF4_C[16] = {
 -1.0f, -0.6961928009986877f, -0.5250730514526367f, -0.39491748809814453f,
 -0.28444138169288635f, -0.18477343022823334f, -0.09105003625154495f, 0.0f,
 0.07958029955625534f, 0.16093020141124725f, 0.24611230194568634f,
 0.33791524171829224f, 0.44070982933044434f, 0.5626170039176941f,
 0.7229568362236023f, 1.0f };

// per-layer f16 weight-cache element offsets
#define WC_LAYER  218103808ull     // elems per layer
#define WC_O      25165824ull
#define WC_G      41943040ull
#define WC_U      100663296ull
#define WC_D      159383552ull

// ---------------- dtype detection (u8 vs i32 idx arrays) ----------------
__global__ void k_detect(const unsigned* __restrict__ p, int* __restrict__ flag){
    if (threadIdx.x == 0){
        int u8 = 0;
        for (int i = 0; i < 256; ++i) if (p[i] >= 16u) { u8 = 1; break; }
        *flag = u8;
    }
}

// ---------------- mega-dequant v2: 8 elems/thread, full-line stores ----------------
// grid = 2 * 106496 blocks; per-layer segments (blocks): q 8192 | k 2048 | v 2048 |
// o 8192 | gate 28672 | up 28672 | down 28672
__global__ __launch_bounds__(256) void k_dequant_all(
        const void* __restrict__ qi, const void* __restrict__ ki, const void* __restrict__ vi,
        const void* __restrict__ oi, const void* __restrict__ gi, const void* __restrict__ ui,
        const void* __restrict__ di,
        const float* __restrict__ qa, const float* __restrict__ ka, const float* __restrict__ va,
        const float* __restrict__ oa, const float* __restrict__ ga, const float* __restrict__ ua,
        const float* __restrict__ da,
        f16* __restrict__ wc, const int* __restrict__ flag)
{
    __shared__ __half2 T[3856];
    int t = threadIdx.x;
    if (t < 256){
        int b0 = t & 15, b1 = t >> 4;
        T[b0 + (b1 << 8)] = __halves2half2(__float2half(NF4_C[b0]), __float2half(NF4_C[b1]));
    }
    __syncthreads();
    int blk = blockIdx.x;
    int l = blk / 106496; blk -= l * 106496;
    const size_t DDc = (size_t)D_ * D_, KVDc = (size_t)KV_ * D_, FDc = (size_t)F_ * D_;
    size_t oDD = (size_t)l * DDc, oKVD = (size_t)l * KVDc, oFD = (size_t)l * FDc;
    f16* wl = wc + (size_t)l * WC_LAYER;
    const void* src; const float* am; size_t so; f16* dst;
    if (blk < 8192)       { src = qi; am = qa; so = oDD;  dst = wl; }
    else if (blk < 10240) { src = ki; am = ka; so = oKVD; dst = wl + DDc;        blk -= 8192; }
    else if (blk < 12288) { src = vi; am = va; so = oKVD; dst = wl + DDc + KVDc; blk -= 10240; }
    else if (blk < 20480) { src = oi; am = oa; so = oDD;  dst = wl + WC_O;       blk -= 12288; }
    else if (blk < 49152) { src = gi; am = ga; so = oFD;  dst = wl + WC_G;       blk -= 20480; }
    else if (blk < 77824) { src = ui; am = ua; so = oFD;  dst = wl + WC_U;       blk -= 49152; }
    else                  { src = di; am = da; so = oFD;  dst = wl + WC_D;       blk -= 77824; }
    size_t i = ((size_t)blk * 256 + t) * 8;          // 8 elems per thread
    float amv = am[(so + i) >> 6];
    __half2 am2 = __float2half2_rn(amv);
    union { __half2 h2[4]; u32x4 u4; } R;
    if (*flag){
        u32x2 u = *(const u32x2*)((const uint8_t*)src + so + i);
        R.h2[0] = __hmul2(T[u.x & 0xFFFFu], am2);
        R.h2[1] = __hmul2(T[u.x >> 16],     am2);
        R.h2[2] = __hmul2(T[u.y & 0xFFFFu], am2);
        R.h2[3] = __hmul2(T[u.y >> 16],     am2);
    } else {
        const i32x4* s4 = (const i32x4*)((const int*)src + so + i);
        i32x4 a0 = s4[0], a1 = s4[1];
        R.h2[0] = __hmul2(T[a0.x | (a0.y << 8)], am2);
        R.h2[1] = __hmul2(T[a0.z | (a0.w << 8)], am2);
        R.h2[2] = __hmul2(T[a1.x | (a1.y << 8)], am2);
        R.h2[3] = __hmul2(T[a1.z | (a1.w << 8)], am2);
    }
    *(u32x4*)(dst + i) = R.u4;                       // one 16B store, wave-contiguous
}

// ---------------- embedding gather (fp32) ----------------
__global__ __launch_bounds__(256) void k_embed(const int* __restrict__ ids,
        const float* __restrict__ E, float* __restrict__ Hh)
{
    int row = blockIdx.x, t = threadIdx.x;
    int id = ids[row];
    const float4* s4 = (const float4*)(E + (size_t)id * D_);
    float4* d4 = (float4*)(Hh + (size_t)row * D_);
    #pragma unroll
    for (int i = 0; i < 4; ++i) d4[t + 256*i] = s4[t + 256*i];
}

// ---------------- RoPE tables ----------------
__global__ __launch_bounds__(256) void k_ropetab(float* __restrict__ cosT, float* __restrict__ sinT){
    int id = blockIdx.x * 256 + threadIdx.x;
    int d = id & 63, s = id >> 6;
    float inv = powf(500000.0f, -(float)d * (1.0f/64.0f));
    float ang = (float)s * inv;
    cosT[id] = cosf(ang);
    sinT[id] = sinf(ang);
}

// ---------------- additive attention mask ----------------
__global__ void k_maskadd(const int* __restrict__ am, float* __restrict__ ma){
    int i = blockIdx.x * 256 + threadIdx.x;
    ma[i] = am[i] ? 0.f : -1e30f;
}

// ---------------- RMSNorm (plain, used once before the loop) ----------------
template<int F16OUT>
__global__ __launch_bounds__(256) void k_rmsnorm(const float* __restrict__ X,
        const float* __restrict__ W, void* __restrict__ outv)
{
    int row = blockIdx.x, t = threadIdx.x;
    const float4* x4 = (const float4*)(X + (size_t)row * D_);
    float4 xs[4]; float ss = 0.f;
    #pragma unroll
    for (int i = 0; i < 4; ++i){
        xs[i] = x4[t + 256*i];
        ss += xs[i].x*xs[i].x + xs[i].y*xs[i].y + xs[i].z*xs[i].z + xs[i].w*xs[i].w;
    }
    for (int m = 32; m; m >>= 1) ss += __shfl_xor(ss, m, 64);
    __shared__ float red[4];
    if ((t & 63) == 0) red[t >> 6] = ss;
    __syncthreads();
    ss = red[0] + red[1] + red[2] + red[3];
    float rs = rsqrtf(ss * (1.0f / D_) + 1e-5f);
    #pragma unroll
    for (int i = 0; i < 4; ++i){
        int c0 = (t + 256*i) * 4;
        float4 wv = *(const float4*)(W + c0);
        float o0 = xs[i].x*rs*wv.x, o1 = xs[i].y*rs*wv.y;
        float o2 = xs[i].z*rs*wv.z, o3 = xs[i].w*rs*wv.w;
        if (F16OUT){
            f16x4 ov = { (f16)o0, (f16)o1, (f16)o2, (f16)o3 };
            *(f16x4*)((f16*)outv + (size_t)row * D_ + c0) = ov;
        } else {
            float4 ov = {o0, o1, o2, o3};
            *(float4*)((float*)outv + (size_t)row * D_ + c0) = ov;
        }
    }
}

// ---------------- fused split-K combine + residual + RMSNorm ----------------
template<int F16OUT>
__global__ __launch_bounds__(256) void k_combnorm(float* __restrict__ H,
        const float* __restrict__ p0, const float* __restrict__ p1,
        const float* __restrict__ W, void* __restrict__ outv)
{
    int row = blockIdx.x, t = threadIdx.x;
    size_t base = (size_t)row * D_;
    float4 xs[4]; float ss = 0.f;
    #pragma unroll
    for (int i = 0; i < 4; ++i){
        int c4 = (t + 256*i) * 4;
        float4 hv = *(const float4*)(H + base + c4);
        float4 a  = *(const float4*)(p0 + base + c4);
        float4 b  = *(const float4*)(p1 + base + c4);
        hv.x += a.x + b.x; hv.y += a.y + b.y; hv.z += a.z + b.z; hv.w += a.w + b.w;
        *(float4*)(H + base + c4) = hv;
        xs[i] = hv;
        ss += hv.x*hv.x + hv.y*hv.y + hv.z*hv.z + hv.w*hv.w;
    }
    for (int m = 32; m; m >>= 1) ss += __shfl_xor(ss, m, 64);
    __shared__ float red[4];
    if ((t & 63) == 0) red[t >> 6] = ss;
    __syncthreads();
    ss = red[0] + red[1] + red[2] + red[3];
    float rs = rsqrtf(ss * (1.0f / D_) + 1e-5f);
    #pragma unroll
    for (int i = 0; i < 4; ++i){
        int c0 = (t + 256*i) * 4;
        float4 wv = *(const float4*)(W + c0);
        float o0 = xs[i].x*rs*wv.x, o1 = xs[i].y*rs*wv.y;
        float o2 = xs[i].z*rs*wv.z, o3 = xs[i].w*rs*wv.w;
        if (F16OUT){
            f16x4 ov = { (f16)o0, (f16)o1, (f16)o2, (f16)o3 };
            *(f16x4*)((f16*)outv + base + c0) = ov;
        } else {
            float4 ov = {o0, o1, o2, o3};
            *(float4*)((float*)outv + base + c0) = ov;
        }
    }
}

// ---------------- merged QKV post-proc: rope(q), rope(k), vtrans(v) ----------------
__global__ __launch_bounds__(256) void k_qkvprep(const f16* __restrict__ qkv,
        f16* __restrict__ qr, f16* __restrict__ kr, f16* __restrict__ vtr,
        const float* __restrict__ cosT, const float* __restrict__ sinT)
{
    const int istr = D_ + 2 * KV_;
    int blk = blockIdx.x;
    if (blk < 16384){                       // rope Q (LNH=5)
        int p = blk * 256 + threadIdx.x;
        int d = p & 63;
        int h = (p >> 6) & 31;
        int s = (p >> 11) & (S_ - 1);
        int b = p >> 21;
        size_t ib = (size_t)(b * S_ + s) * istr + (size_t)h * HD_;
        float x1 = (float)qkv[ib + d], x2 = (float)qkv[ib + 64 + d];
        float c = cosT[s*64 + d], sn = sinT[s*64 + d];
        size_t ob = (((size_t)((b << 5) + h)) * S_ + (size_t)s) * HD_;
        qr[ob + d]      = (f16)(x1 * c - x2 * sn);
        qr[ob + 64 + d] = (f16)(x2 * c + x1 * sn);
    } else if (blk < 20480){                // rope K (LNH=3)
        int p = (blk - 16384) * 256 + threadIdx.x;
        int d = p & 63;
        int h = (p >> 6) & 7;
        int s = (p >> 9) & (S_ - 1);
        int b = p >> 19;
        size_t ib = (size_t)(b * S_ + s) * istr + (size_t)(D_) + (size_t)h * HD_;
        float x1 = (float)qkv[ib + d], x2 = (float)qkv[ib + 64 + d];
        float c = cosT[s*64 + d], sn = sinT[s*64 + d];
        size_t ob = (((size_t)((b << 3) + h)) * S_ + (size_t)s) * HD_;
        kr[ob + d]      = (f16)(x1 * c - x2 * sn);
        kr[ob + 64 + d] = (f16)(x2 * c + x1 * sn);
    } else {                                // V transpose
        int p = (blk - 20480) * 256 + threadIdx.x;
        int s  = p & (S_ - 1);
        int d  = (p >> 10) & (HD_ - 1);
        int hk = (p >> 17) & (HK_ - 1);
        int b  = p >> 20;
        f16 v = qkv[(size_t)(b * S_ + s) * istr + (size_t)(D_ + KV_) + (size_t)hk * HD_ + d];
        vtr[(((size_t)(b * HK_ + hk)) * HD_ + d) * S_ + s] = v;
    }
}

// ---------------- fused flash attention ----------------
__global__ __launch_bounds__(256) void k_flash(const f16* __restrict__ Qr, const f16* __restrict__ Kr,
        const f16* __restrict__ Vt, const float* __restrict__ mAddG, f16* __restrict__ ctx)
{
    __shared__ f16 KS[8192];
    __shared__ f16 VS[8192];
    __shared__ f16 PS[8192];
    const int t = threadIdx.x;
    const int w = t >> 6, l = t & 63;
    const int lr = l & 15, lg = l >> 4;
    const int qt = blockIdx.x, bh = blockIdx.y;
    const int b = bh >> 5, hh = bh & 31, hk = hh >> 2;
    const f16* Qb = Qr + ((size_t)bh * S_ + (size_t)qt*128) * HD_;
    const f16* Kb = Kr + (size_t)(b * HK_ + hk) * S_ * HD_;
    const f16* Vb = Vt + (size_t)(b * HK_ + hk) * HD_ * S_;

    auto stage16x128 = [&](const f16* src, int lds_, f16* dst){
        int rowl = t >> 4;
        int cs = ((t & 15) ^ (rowl & 7)) << 3;
        #pragma unroll
        for (int g = 0; g < 4; ++g)
            __builtin_amdgcn_global_load_lds(AS1(src + (size_t)(g*16 + rowl)*lds_ + cs),
                AS3(dst + g*2048 + w*512), 16, 0, 0);
    };
    auto stage32x64 = [&](const f16* src, int lds_, f16* dst){
        int rowl = t >> 3;
        int cs = ((t & 7) ^ (rowl & 7)) << 3;
        #pragma unroll
        for (int g = 0; g < 4; ++g)
            __builtin_amdgcn_global_load_lds(AS1(src + (size_t)(g*32 + rowl)*lds_ + cs),
                AS3(dst + g*2048 + w*512), 16, 0, 0);
    };

    stage16x128(Qb, HD_, KS);
    stage16x128(Qb + 64*HD_, HD_, VS);
    __syncthreads();
    f16x8 qF[2][4];
    {
        const f16* qsrc = (w < 2) ? KS : VS;
        int rbase = (w & 1) * 32;
        #pragma unroll
        for (int m = 0; m < 2; ++m)
            #pragma unroll
            for (int kd = 0; kd < 4; ++kd){
                int row = rbase + m*16 + lr;
                qF[m][kd] = *(const f16x8*)&qsrc[row*128 + (((kd*4 + lg) ^ (row & 7)) << 3)];
            }
    }
    __syncthreads();

    float mrow[2][4], lrow[2][4];
    f32x4 oacc[2][8];
    #pragma unroll
    for (int m = 0; m < 2; ++m)
        #pragma unroll
        for (int r = 0; r < 4; ++r){ mrow[m][r] = -1e30f; lrow[m][r] = 0.f; }
    #pragma unroll
    for (int m = 0; m < 2; ++m)
        #pragma unroll
        for (int dn = 0; dn < 8; ++dn){ f32x4 z = {0,0,0,0}; oacc[m][dn] = z; }

    const float ISQ = 0.08838834764831845f;
    const int ktMax = 2*qt + 1;

    for (int kt = 0; kt <= ktMax; ++kt){
        stage16x128(Kb + (size_t)(kt*64)*HD_, HD_, KS);
        __syncthreads();

        f32x4 sacc[2][4];
        #pragma unroll
        for (int m = 0; m < 2; ++m)
            #pragma unroll
            for (int n = 0; n < 4; ++n){ f32x4 z = {0,0,0,0}; sacc[m][n] = z; }
        #pragma unroll
        for (int n = 0; n < 4; ++n){
            int krow = n*16 + lr;
            #pragma unroll
            for (int kd = 0; kd < 4; ++kd){
                f16x8 kF = *(const f16x8*)&KS[krow*128 + (((kd*4 + lg) ^ (krow & 7)) << 3)];
                #pragma unroll
                for (int m = 0; m < 2; ++m)
                    sacc[m][n] = __builtin_amdgcn_mfma_f32_16x16x32_f16(qF[m][kd], kF, sacc[m][n], 0, 0, 0);
            }
        }

        stage32x64(Vb + kt*64, S_, VS);

        float mAdd[4];
        #pragma unroll
        for (int n = 0; n < 4; ++n) mAdd[n] = mAddG[b*S_ + kt*64 + n*16 + lr];
        int diag = (kt >= 2*qt);
        #pragma unroll
        for (int m = 0; m < 2; ++m)
        #pragma unroll
        for (int n = 0; n < 4; ++n)
        #pragma unroll
        for (int r = 0; r < 4; ++r){
            float s = sacc[m][n][r] * ISQ + mAdd[n];
            if (diag && (kt*64 + n*16 + lr) > (qt*128 + w*32 + m*16 + lg*4 + r)) s = -1e30f;
            sacc[m][n][r] = s;
        }
        #pragma unroll
        for (int m = 0; m < 2; ++m)
        #pragma unroll
        for (int r = 0; r < 4; ++r){
            float tm = fmaxf(fmaxf(sacc[m][0][r], sacc[m][1][r]), fmaxf(sacc[m][2][r], sacc[m][3][r]));
            #pragma unroll
            for (int msk = 1; msk < 16; msk <<= 1) tm = fmaxf(tm, __shfl_xor(tm, msk, 64));
            float mn = fmaxf(mrow[m][r], tm);
            float scl = __expf(mrow[m][r] - mn);
            mrow[m][r] = mn;
            float rs = 0.f;
            #pragma unroll
            for (int n = 0; n < 4; ++n){
                float p = __expf(sacc[m][n][r] - mn);
                sacc[m][n][r] = p; rs += p;
            }
            #pragma unroll
            for (int msk = 1; msk < 16; msk <<= 1) rs += __shfl_xor(rs, msk, 64);
            lrow[m][r] = lrow[m][r] * scl + rs;
            #pragma unroll
            for (int dn = 0; dn < 8; ++dn) oacc[m][dn][r] *= scl;
        }
        #pragma unroll
        for (int m = 0; m < 2; ++m)
        #pragma unroll
        for (int n = 0; n < 4; ++n)
        #pragma unroll
        for (int r = 0; r < 4; ++r){
            int rowl = m*16 + lg*4 + r;
            int slot = (n*2 + (lr >> 3)) ^ (rowl & 7);
            PS[w*2048 + rowl*64 + slot*8 + (lr & 7)] = (f16)sacc[m][n][r];
        }
        __syncthreads();

        f16x8 pF[2][2];
        #pragma unroll
        for (int m = 0; m < 2; ++m)
            #pragma unroll
            for (int kd = 0; kd < 2; ++kd){
                int prow = m*16 + lr;
                pF[m][kd] = *(const f16x8*)&PS[w*2048 + prow*64 + (((kd*4 + lg) ^ (prow & 7)) << 3)];
            }
        #pragma unroll
        for (int dn = 0; dn < 8; ++dn){
            int vrow = dn*16 + lr;
            #pragma unroll
            for (int kd = 0; kd < 2; ++kd){
                f16x8 vF = *(const f16x8*)&VS[vrow*64 + (((kd*4 + lg) ^ (vrow & 7)) << 3)];
                #pragma unroll
                for (int m = 0; m < 2; ++m)
                    oacc[m][dn] = __builtin_amdgcn_mfma_f32_16x16x32_f16(pF[m][kd], vF, oacc[m][dn], 0, 0, 0);
            }
        }
        __syncthreads();
    }

    #pragma unroll
    for (int m = 0; m < 2; ++m)
    #pragma unroll
    for (int dn = 0; dn < 8; ++dn)
    #pragma unroll
    for (int r = 0; r < 4; ++r){
        int grow = qt*128 + w*32 + m*16 + lg*4 + r;
        int gcol = hh*128 + dn*16 + lr;
        float v = oacc[m][dn][r] / fmaxf(lrow[m][r], 1e-30f);
        ctx[((size_t)(b * S_) + grow) * D_ + gcol] = (f16)v;
    }
}

// ---------------- 256x256 8-phase pipelined GEMM (T2+T3+T4+T5, 16x16x32) ----------------
template<int OUT>
__global__ __launch_bounds__(512, 1) void k_gemm3(const f16* __restrict__ A, const f16* __restrict__ Bp,
        void* __restrict__ Cv, const f16* __restrict__ G, int Kd, int ldk, int ldc)
{
    __shared__ f16 LDS[65536];
    const int t = threadIdx.x;
    const int w = t >> 6, l = t & 63;
    const int wm = w >> 2, wn = w & 3;

    int gx = gridDim.x, gy = gridDim.y;
    int nWG = gx * gy * gridDim.z;
    int n = (blockIdx.z * gy + blockIdx.y) * gx + blockIdx.x;
    int q = nWG >> 3;
    int sw = (n & 7) * q + (n >> 3);
    int by = sw % gy; int r1 = sw / gy; int bx = r1 % gx; int bz = r1 / gx;

    const int row0 = by * 256, col0 = bx * 256;
    const size_t koff = (size_t)bz * Kd;
    const int NT = Kd >> 6;

    const int swzk = ((t & 7) ^ ((t >> 3) & 7)) * 8;
    const f16* pA[2]; const f16* pB[2];
    #pragma unroll
    for (int l2 = 0; l2 < 2; ++l2){
        pA[l2] = A  + (size_t)(row0 + l2*128 + (t >> 3)) * ldk + koff + swzk;
        int wnc = (l2*64 + (t >> 3)) >> 5;
        pB[l2] = Bp + (size_t)(col0 + wnc*64 + ((t >> 3) & 31)) * ldk + koff + swzk;
    }

    auto stA = [&](int g, int tt, int buf){
        size_t so = (size_t)tt * 64;
        #pragma unroll
        for (int l2 = 0; l2 < 2; ++l2)
            __builtin_amdgcn_global_load_lds(AS1(pA[l2] + (size_t)g*64*ldk + so),
                AS3(&LDS[buf*16384 + g*8192 + l2*4096 + w*512]), 16, 0, 0);
    };
    auto stB = [&](int g, int tt, int buf){
        size_t so = (size_t)tt * 64;
        #pragma unroll
        for (int l2 = 0; l2 < 2; ++l2)
            __builtin_amdgcn_global_load_lds(AS1(pB[l2] + (size_t)g*32*ldk + so),
                AS3(&LDS[32768 + buf*16384 + g*8192 + l2*4096 + w*512]), 16, 0, 0);
    };

    const int lrow = (l & 15) * 64;
    const int kp0 = (((l >> 4))     ^ (l & 7)) * 8;
    const int kp1 = ((4 + (l >> 4)) ^ (l & 7)) * 8;

    f16x8 aR[2][4], bR0[2][2], bR1[2][2];
    auto rdA = [&](int g, int buf){
        int base = buf*16384 + g*8192 + wm*4096 + lrow;
        #pragma unroll
        for (int mf = 0; mf < 4; ++mf){
            aR[0][mf] = *(const f16x8*)&LDS[base + mf*1024 + kp0];
            aR[1][mf] = *(const f16x8*)&LDS[base + mf*1024 + kp1];
        }
    };
    auto rdB = [&](int g, int buf, f16x8 (&bR)[2][2]){
        int base = 32768 + buf*16384 + g*8192 + wn*2048 + lrow;
        #pragma unroll
        for (int nf = 0; nf < 2; ++nf){
            bR[0][nf] = *(const f16x8*)&LDS[base + nf*1024 + kp0];
            bR[1][nf] = *(const f16x8*)&LDS[base + nf*1024 + kp1];
        }
    };

    f32x4 zero = {0.f, 0.f, 0.f, 0.f};
    f32x4 acc[8][4];
    #pragma unroll
    for (int mi = 0; mi < 8; ++mi)
        #pragma unroll
        for (int ni = 0; ni < 4; ++ni) acc[mi][ni] = zero;

    #define MMQ(qm, qn, bR) { \
        __builtin_amdgcn_s_setprio(1); \
        _Pragma("unroll") \
        for (int ks = 0; ks < 2; ++ks) \
            _Pragma("unroll") \
            for (int mf = 0; mf < 4; ++mf) \
                _Pragma("unroll") \
                for (int nf = 0; nf < 2; ++nf) \
                    acc[(qm)*4+mf][(qn)*2+nf] = __builtin_amdgcn_mfma_f32_16x16x32_f16(aR[ks][mf], bR[ks][nf], acc[(qm)*4+mf][(qn)*2+nf], 0, 0, 0); \
        __builtin_amdgcn_s_setprio(0); }
    #define LGKM0 { asm volatile("s_waitcnt lgkmcnt(0)" ::: "memory"); __builtin_amdgcn_sched_barrier(0); }
    #define VM4   { asm volatile("s_waitcnt vmcnt(4)" ::: "memory"); }
    #define BAR   __builtin_amdgcn_s_barrier()

    stA(0, 0, 0); stB(1, 0, 0); stA(1, 0, 0); stB(0, 0, 0);
    if (NT > 1){ stA(0, 1, 1); stB(1, 1, 1); }
    VM4; BAR;

    for (int tt = 0; tt < NT; tt += 2){
        int c2 = (tt + 2 < NT) ? tt + 2 : NT - 1;
        int c3 = (tt + 3 < NT) ? tt + 3 : NT - 1;
        rdA(0, 0); rdB(0, 0, bR0);
        stA(1, tt+1 < NT ? tt+1 : NT-1, 1); stB(0, tt+1 < NT ? tt+1 : NT-1, 1);
        BAR; LGKM0; MMQ(0, 0, bR0); BAR;
        rdB(1, 0, bR1);
        BAR; LGKM0; MMQ(0, 1, bR1); BAR;
        rdA(1, 0);
        stA(0, c2, 0);
        BAR; LGKM0; MMQ(1, 1, bR1); BAR;
        stB(1, c2, 0);
        BAR; MMQ(1, 0, bR0); VM4; BAR;
        rdA(0, 1); rdB(0, 1, bR0);
        stA(1, c2, 0); stB(0, c2, 0);
        BAR; LGKM0; MMQ(0, 0, bR0); BAR;
        rdB(1, 1, bR1);
        BAR; LGKM0; MMQ(0, 1, bR1); BAR;
        rdA(1, 1);
        stA(0, c3, 1);
        BAR; LGKM0; MMQ(1, 1, bR1); BAR;
        stB(1, c3, 1);
        BAR; MMQ(1, 0, bR0); VM4; BAR;
    }

    #pragma unroll
    for (int mi = 0; mi < 8; ++mi)
    #pragma unroll
    for (int ni = 0; ni < 4; ++ni)
    #pragma unroll
    for (int r = 0; r < 4; ++r){
        int row = row0 + wm*128 + mi*16 + ((l >> 4) << 2) + r;
        int col = col0 + wn*64  + ni*16 + (l & 15);
        float v = acc[mi][ni][r];
        if (OUT == 0){
            ((float*)Cv)[(size_t)bz * ((size_t)M_ * ldc) + (size_t)row * ldc + col] = v;
        } else if (OUT == 2){
            ((f16*)Cv)[(size_t)row * ldc + col] = (f16)v;
        } else {
            size_t idx = (size_t)row * ldc + col;
            float g = (float)G[idx];
            float sg = g / (1.f + __expf(-g));
            ((f16*)Cv)[idx] = (f16)(sg * v);
        }
    }
    #undef MMQ
    #undef LGKM0
    #undef VM4
    #undef BAR
}

// ---------------- masked mean pool, 2-stage ----------------
__global__ __launch_bounds__(256) void k_pool1(const float* __restrict__ Hn, const int* __restrict__ amask,
        float* __restrict__ part, float* __restrict__ cntp)
{
    int d0 = blockIdx.x * 256 + threadIdx.x;
    int b  = blockIdx.y;
    int z  = blockIdx.z;
    int s0 = z * 128;
    float s = 0.f;
    for (int i = 0; i < 128; ++i){
        int row = s0 + i;
        if (amask[b * S_ + row])
            s += Hn[((size_t)(b * S_ + row)) * D_ + d0];
    }
    part[((size_t)(z * B_ + b)) * D_ + d0] = s;
    if (blockIdx.x == 0 && threadIdx.x == 0){
        float c = 0.f;
        for (int i = 0; i < 128; ++i) c += (amask[b * S_ + s0 + i] != 0) ? 1.f : 0.f;
        cntp[z * B_ + b] = c;
    }
}
__global__ __launch_bounds__(256) void k_pool2(const float* __restrict__ part, const float* __restrict__ cntp,
        float* __restrict__ outp)
{
    int gid = blockIdx.x * 256 + threadIdx.x;
    int b = gid >> 12, d = gid & (D_ - 1);
    float s = 0.f, c = 0.f;
    #pragma unroll
    for (int z = 0; z < 8; ++z){
        s += part[((size_t)(z * B_ + b)) * D_ + d];
        c += cntp[z * B_ + b];
    }
    outp[gid] = s / fmaxf(c, 1e-9f);
}

// ---------------- launch ----------------
extern "C" void kernel_launch(void* const* d_in, const int* in_sizes, int n_in,
                              void* d_out, int out_size, void* d_ws, size_t ws_size,
                              hipStream_t stream)
{
    (void)in_sizes; (void)n_in; (void)out_size; (void)ws_size;
    const int*   ids   = (const int*)  d_in[0];
    const int*   amask = (const int*)  d_in[1];
    const float* embed = (const float*)d_in[2];
    const void*  qi = d_in[3];  const float* qa = (const float*)d_in[4];
    const void*  ki = d_in[5];  const float* ka = (const float*)d_in[6];
    const void*  vi = d_in[7];  const float* va = (const float*)d_in[8];
    const void*  oi = d_in[9];  const float* oa = (const float*)d_in[10];
    const void*  gi = d_in[11]; const float* ga = (const float*)d_in[12];
    const void*  ui = d_in[13]; const float* ua = (const float*)d_in[14];
    const void*  di = d_in[15]; const float* da = (const float*)d_in[16];
    const float* ln1 = (const float*)d_in[17];
    const float* ln2 = (const float*)d_in[18];
    const float* lnf = (const float*)d_in[19];

    char* ws = (char*)d_ws;
    int*   flag = (int*)ws;
    float* h    = (float*)(ws + 256);
    float* cosT = (float*)(ws + 256 + 33554432);
    float* sinT = cosT + 65536;
    f16*   xin  = (f16*)(ws + 34078976);
    char*  R4   = ws + 168296704;
    f16* qkv16 = (f16*)(R4);
    f16* qr  = (f16*)(R4 + 25165824);
    f16* kr  = (f16*)(R4 + 41943040);
    f16* vtr = (f16*)(R4 + 46137344);
    f16* ctx = (f16*)(R4 + 50331648);
    char* R5 = R4 + 67108864;
    f16*    gbuf   = (f16*)R5;
    float*  pR5_0  = (float*)R5;
    float*  pR5_1  = (float*)(R5 + 33554432);
    float*  pR4_0  = (float*)R4;
    float*  pR4_1  = (float*)(R4 + 33554432);
    float*  hn     = (float*)R4;
    float*  part   = (float*)R5;
    float*  cntp   = (float*)(R5 + 1048576);
    float*  maskAdd= (float*)(ws + 310378496);
    f16*    wc     = (f16*)(ws + 335544320);   // 872.4 MB weight cache (both layers)

    const int QKV_N = D_ + 2 * KV_;

    k_detect <<<1, 64, 0, stream>>>((const unsigned*)qi, flag);
    k_dequant_all<<<2*106496, 256, 0, stream>>>(qi, ki, vi, oi, gi, ui, di,
            qa, ka, va, oa, ga, ua, da, wc, flag);
    k_embed  <<<M_, 256, 0, stream>>>(ids, embed, h);
    k_ropetab<<<256, 256, 0, stream>>>(cosT, sinT);
    k_maskadd<<<(B_*S_)/256, 256, 0, stream>>>(amask, maskAdd);
    k_rmsnorm<1><<<M_, 256, 0, stream>>>(h, ln1, xin);      // layer-0 input norm

    for (int l = 0; l < 2; ++l){
        f16* wcl = wc + (size_t)l * WC_LAYER;

        // QKV projection from weight cache
        k_gemm3<2><<<dim3(QKV_N/256, M_/256, 1), 512, 0, stream>>>(xin, wcl, qkv16, nullptr, D_, D_, QKV_N);
        k_qkvprep<<<28672, 256, 0, stream>>>(qkv16, qr, kr, vtr, cosT, sinT);

        // fused flash attention
        k_flash<<<dim3(S_/128, B_*H_), 256, 0, stream>>>(qr, kr, vtr, maskAdd, ctx);

        // O projection (split-K x2) + fused residual + ln2 norm
        k_gemm3<0><<<dim3(D_/256, M_/256, 2), 512, 0, stream>>>(ctx, wcl + WC_O, pR5_0, nullptr, D_/2, D_, D_);
        k_combnorm<1><<<M_, 256, 0, stream>>>(h, pR5_0, pR5_1, ln2 + l * D_, xin);

        // MLP from weight cache
        k_gemm3<2><<<dim3(F_/256, M_/256, 1), 512, 0, stream>>>(xin, wcl + WC_G, gbuf, nullptr, D_, D_, F_);
        k_gemm3<3><<<dim3(F_/256, M_/256, 1), 512, 0, stream>>>(xin, wcl + WC_U, gbuf, gbuf, D_, D_, F_);
        k_gemm3<0><<<dim3(D_/256, M_/256, 2), 512, 0, stream>>>(gbuf, wcl + WC_D, pR4_0, nullptr, F_/2, F_, D_);

        // down combine + residual + next-input norm (ln1[1] for l=0, final lnf for l=1)
        if (l == 0)
            k_combnorm<1><<<M_, 256, 0, stream>>>(h, pR4_0, pR4_1, ln1 + D_, xin);
        else
            k_combnorm<0><<<M_, 256, 0, stream>>>(h, pR4_0, pR4_1, lnf, hn);
    }

    k_pool1<<<dim3(D_/256, B_, 8), 256, 0, stream>>>(hn, amask, part, cntp);
    k_pool2<<<(B_*D_)/256, 256, 0, stream>>>(part, cntp, (float*)d_out);
}

// Round 17
// 2422.332 us; speedup vs baseline: 2.1816x; 1.0065x over previous
//
#include <hip/hip_runtime.h>
#include <hip/hip_fp16.h>
#include <cstdint>
#include <cstddef>

// ---------------- problem constants ----------------
#define B_  2
#define S_  1024
#define D_  4096
#define KV_ 1024
#define F_  14336
#define H_  32
#define HK_ 8
#define HD_ 128
#define M_  2048   // B*S

typedef _Float16 f16;
typedef f16   f16x8 __attribute__((ext_vector_type(8)));
typedef f16   f16x4 __attribute__((ext_vector_type(4)));
typedef float f32x4 __attribute__((ext_vector_type(4)));
typedef unsigned u32x2 __attribute__((ext_vector_type(2)));
typedef unsigned u32x4 __attribute__((ext_vector_type(4)));
typedef int      i32x4 __attribute__((ext_vector_type(4)));

#define AS1(p) ((const __attribute__((address_space(1))) void*)(p))
#define AS3(p) ((__attribute__((address_space(3))) void*)(p))

__device__ __constant__ float NF4_C[16] = {
 -1.0f, -0.6961928009986877f, -0.5250730514526367f, -0.39491748809814453f,
 -0.28444138169288635f, -0.18477343022823334f, -0.09105003625154495f, 0.0f,
 0.07958029955625534f, 0.16093020141124725f, 0.24611230194568634f,
 0.33791524171829224f, 0.44070982933044434f, 0.5626170039176941f,
 0.7229568362236023f, 1.0f };

// per-layer f16 weight-cache element offsets
#define WC_LAYER  218103808ull     // elems per layer
#define WC_O      25165824ull
#define WC_G      41943040ull
#define WC_U      100663296ull
#define WC_D      159383552ull

// ---------------- dtype detection (u8 vs i32 idx arrays) ----------------
__global__ void k_detect(const unsigned* __restrict__ p, int* __restrict__ flag){
    if (threadIdx.x == 0){
        int u8 = 0;
        for (int i = 0; i < 256; ++i) if (p[i] >= 16u) { u8 = 1; break; }
        *flag = u8;
    }
}

// ---------------- mega-dequant v2: 8 elems/thread, full-line stores ----------------
__global__ __launch_bounds__(256) void k_dequant_all(
        const void* __restrict__ qi, const void* __restrict__ ki, const void* __restrict__ vi,
        const void* __restrict__ oi, const void* __restrict__ gi, const void* __restrict__ ui,
        const void* __restrict__ di,
        const float* __restrict__ qa, const float* __restrict__ ka, const float* __restrict__ va,
        const float* __restrict__ oa, const float* __restrict__ ga, const float* __restrict__ ua,
        const float* __restrict__ da,
        f16* __restrict__ wc, const int* __restrict__ flag)
{
    __shared__ __half2 T[3856];
    int t = threadIdx.x;
    if (t < 256){
        int b0 = t & 15, b1 = t >> 4;
        T[b0 + (b1 << 8)] = __halves2half2(__float2half(NF4_C[b0]), __float2half(NF4_C[b1]));
    }
    __syncthreads();
    int blk = blockIdx.x;
    int l = blk / 106496; blk -= l * 106496;
    const size_t DDc = (size_t)D_ * D_, KVDc = (size_t)KV_ * D_, FDc = (size_t)F_ * D_;
    size_t oDD = (size_t)l * DDc, oKVD = (size_t)l * KVDc, oFD = (size_t)l * FDc;
    f16* wl = wc + (size_t)l * WC_LAYER;
    const void* src; const float* am; size_t so; f16* dst;
    if (blk < 8192)       { src = qi; am = qa; so = oDD;  dst = wl; }
    else if (blk < 10240) { src = ki; am = ka; so = oKVD; dst = wl + DDc;        blk -= 8192; }
    else if (blk < 12288) { src = vi; am = va; so = oKVD; dst = wl + DDc + KVDc; blk -= 10240; }
    else if (blk < 20480) { src = oi; am = oa; so = oDD;  dst = wl + WC_O;       blk -= 12288; }
    else if (blk < 49152) { src = gi; am = ga; so = oFD;  dst = wl + WC_G;       blk -= 20480; }
    else if (blk < 77824) { src = ui; am = ua; so = oFD;  dst = wl + WC_U;       blk -= 49152; }
    else                  { src = di; am = da; so = oFD;  dst = wl + WC_D;       blk -= 77824; }
    size_t i = ((size_t)blk * 256 + t) * 8;          // 8 elems per thread
    float amv = am[(so + i) >> 6];
    __half2 am2 = __float2half2_rn(amv);
    union { __half2 h2[4]; u32x4 u4; } R;
    if (*flag){
        u32x2 u = *(const u32x2*)((const uint8_t*)src + so + i);
        R.h2[0] = __hmul2(T[u.x & 0xFFFFu], am2);
        R.h2[1] = __hmul2(T[u.x >> 16],     am2);
        R.h2[2] = __hmul2(T[u.y & 0xFFFFu], am2);
        R.h2[3] = __hmul2(T[u.y >> 16],     am2);
    } else {
        const i32x4* s4 = (const i32x4*)((const int*)src + so + i);
        i32x4 a0 = s4[0], a1 = s4[1];
        R.h2[0] = __hmul2(T[a0.x | (a0.y << 8)], am2);
        R.h2[1] = __hmul2(T[a0.z | (a0.w << 8)], am2);
        R.h2[2] = __hmul2(T[a1.x | (a1.y << 8)], am2);
        R.h2[3] = __hmul2(T[a1.z | (a1.w << 8)], am2);
    }
    *(u32x4*)(dst + i) = R.u4;
}

// ---------------- embedding gather (fp32) ----------------
__global__ __launch_bounds__(256) void k_embed(const int* __restrict__ ids,
        const float* __restrict__ E, float* __restrict__ Hh)
{
    int row = blockIdx.x, t = threadIdx.x;
    int id = ids[row];
    const float4* s4 = (const float4*)(E + (size_t)id * D_);
    float4* d4 = (float4*)(Hh + (size_t)row * D_);
    #pragma unroll
    for (int i = 0; i < 4; ++i) d4[t + 256*i] = s4[t + 256*i];
}

// ---------------- RoPE tables ----------------
__global__ __launch_bounds__(256) void k_ropetab(float* __restrict__ cosT, float* __restrict__ sinT){
    int id = blockIdx.x * 256 + threadIdx.x;
    int d = id & 63, s = id >> 6;
    float inv = powf(500000.0f, -(float)d * (1.0f/64.0f));
    float ang = (float)s * inv;
    cosT[id] = cosf(ang);
    sinT[id] = sinf(ang);
}

// ---------------- additive attention mask ----------------
__global__ void k_maskadd(const int* __restrict__ am, float* __restrict__ ma){
    int i = blockIdx.x * 256 + threadIdx.x;
    ma[i] = am[i] ? 0.f : -1e30f;
}

// ---------------- RMSNorm (plain, used once before the loop) ----------------
template<int F16OUT>
__global__ __launch_bounds__(256) void k_rmsnorm(const float* __restrict__ X,
        const float* __restrict__ W, void* __restrict__ outv)
{
    int row = blockIdx.x, t = threadIdx.x;
    const float4* x4 = (const float4*)(X + (size_t)row * D_);
    float4 xs[4]; float ss = 0.f;
    #pragma unroll
    for (int i = 0; i < 4; ++i){
        xs[i] = x4[t + 256*i];
        ss += xs[i].x*xs[i].x + xs[i].y*xs[i].y + xs[i].z*xs[i].z + xs[i].w*xs[i].w;
    }
    for (int m = 32; m; m >>= 1) ss += __shfl_xor(ss, m, 64);
    __shared__ float red[4];
    if ((t & 63) == 0) red[t >> 6] = ss;
    __syncthreads();
    ss = red[0] + red[1] + red[2] + red[3];
    float rs = rsqrtf(ss * (1.0f / D_) + 1e-5f);
    #pragma unroll
    for (int i = 0; i < 4; ++i){
        int c0 = (t + 256*i) * 4;
        float4 wv = *(const float4*)(W + c0);
        float o0 = xs[i].x*rs*wv.x, o1 = xs[i].y*rs*wv.y;
        float o2 = xs[i].z*rs*wv.z, o3 = xs[i].w*rs*wv.w;
        if (F16OUT){
            f16x4 ov = { (f16)o0, (f16)o1, (f16)o2, (f16)o3 };
            *(f16x4*)((f16*)outv + (size_t)row * D_ + c0) = ov;
        } else {
            float4 ov = {o0, o1, o2, o3};
            *(float4*)((float*)outv + (size_t)row * D_ + c0) = ov;
        }
    }
}

// ---------------- fused split-K combine + residual + RMSNorm ----------------
template<int F16OUT>
__global__ __launch_bounds__(256) void k_combnorm(float* __restrict__ H,
        const float* __restrict__ p0, const float* __restrict__ p1,
        const float* __restrict__ W, void* __restrict__ outv)
{
    int row = blockIdx.x, t = threadIdx.x;
    size_t base = (size_t)row * D_;
    float4 xs[4]; float ss = 0.f;
    #pragma unroll
    for (int i = 0; i < 4; ++i){
        int c4 = (t + 256*i) * 4;
        float4 hv = *(const float4*)(H + base + c4);
        float4 a  = *(const float4*)(p0 + base + c4);
        float4 b  = *(const float4*)(p1 + base + c4);
        hv.x += a.x + b.x; hv.y += a.y + b.y; hv.z += a.z + b.z; hv.w += a.w + b.w;
        *(float4*)(H + base + c4) = hv;
        xs[i] = hv;
        ss += hv.x*hv.x + hv.y*hv.y + hv.z*hv.z + hv.w*hv.w;
    }
    for (int m = 32; m; m >>= 1) ss += __shfl_xor(ss, m, 64);
    __shared__ float red[4];
    if ((t & 63) == 0) red[t >> 6] = ss;
    __syncthreads();
    ss = red[0] + red[1] + red[2] + red[3];
    float rs = rsqrtf(ss * (1.0f / D_) + 1e-5f);
    #pragma unroll
    for (int i = 0; i < 4; ++i){
        int c0 = (t + 256*i) * 4;
        float4 wv = *(const float4*)(W + c0);
        float o0 = xs[i].x*rs*wv.x, o1 = xs[i].y*rs*wv.y;
        float o2 = xs[i].z*rs*wv.z, o3 = xs[i].w*rs*wv.w;
        if (F16OUT){
            f16x4 ov = { (f16)o0, (f16)o1, (f16)o2, (f16)o3 };
            *(f16x4*)((f16*)outv + base + c0) = ov;
        } else {
            float4 ov = {o0, o1, o2, o3};
            *(float4*)((float*)outv + base + c0) = ov;
        }
    }
}

// ---------------- QKV post-proc v2: vectorized rope + LDS-transpose V ----------------
// grid = 2048 (ropeQ) + 512 (ropeK) + 256 (vtrans) = 2816 blocks x 256
__global__ __launch_bounds__(256) void k_qkvprep(const f16* __restrict__ qkv,
        f16* __restrict__ qr, f16* __restrict__ kr, f16* __restrict__ vtr,
        const float* __restrict__ cosT, const float* __restrict__ sinT)
{
    const int istr = D_ + 2 * KV_;
    int blk = blockIdx.x;
    int t = threadIdx.x;
    if (blk < 2048){                        // rope Q: 16 elems/thread (8 low-d + 8 high-d)
        int p = blk * 256 + t;              // 2^19 threads total
        int d0 = (p & 7) * 8;
        int h  = (p >> 3) & 31;
        int s  = (p >> 8) & (S_ - 1);
        int b  = p >> 18;
        size_t ib = (size_t)(b * S_ + s) * istr + (size_t)h * HD_;
        f16x8 x1 = *(const f16x8*)(qkv + ib + d0);
        f16x8 x2 = *(const f16x8*)(qkv + ib + 64 + d0);
        f32x4 c0 = *(const f32x4*)(cosT + s*64 + d0);
        f32x4 c1 = *(const f32x4*)(cosT + s*64 + d0 + 4);
        f32x4 s0 = *(const f32x4*)(sinT + s*64 + d0);
        f32x4 s1 = *(const f32x4*)(sinT + s*64 + d0 + 4);
        f16x8 o1, o2;
        #pragma unroll
        for (int j = 0; j < 8; ++j){
            float c = (j < 4) ? c0[j] : c1[j-4];
            float sn = (j < 4) ? s0[j] : s1[j-4];
            float a = (float)x1[j], bb = (float)x2[j];
            o1[j] = (f16)(a * c - bb * sn);
            o2[j] = (f16)(bb * c + a * sn);
        }
        size_t ob = (((size_t)((b << 5) + h)) * S_ + (size_t)s) * HD_;
        *(f16x8*)(qr + ob + d0)      = o1;
        *(f16x8*)(qr + ob + 64 + d0) = o2;
    } else if (blk < 2560){                 // rope K
        int p = (blk - 2048) * 256 + t;     // 2^17 threads total
        int d0 = (p & 7) * 8;
        int hk = (p >> 3) & 7;
        int s  = (p >> 6) & (S_ - 1);
        int b  = p >> 16;
        size_t ib = (size_t)(b * S_ + s) * istr + (size_t)D_ + (size_t)hk * HD_;
        f16x8 x1 = *(const f16x8*)(qkv + ib + d0);
        f16x8 x2 = *(const f16x8*)(qkv + ib + 64 + d0);
        f32x4 c0 = *(const f32x4*)(cosT + s*64 + d0);
        f32x4 c1 = *(const f32x4*)(cosT + s*64 + d0 + 4);
        f32x4 s0 = *(const f32x4*)(sinT + s*64 + d0);
        f32x4 s1 = *(const f32x4*)(sinT + s*64 + d0 + 4);
        f16x8 o1, o2;
        #pragma unroll
        for (int j = 0; j < 8; ++j){
            float c = (j < 4) ? c0[j] : c1[j-4];
            float sn = (j < 4) ? s0[j] : s1[j-4];
            float a = (float)x1[j], bb = (float)x2[j];
            o1[j] = (f16)(a * c - bb * sn);
            o2[j] = (f16)(bb * c + a * sn);
        }
        size_t ob = (((size_t)((b << 3) + hk)) * S_ + (size_t)s) * HD_;
        *(f16x8*)(kr + ob + d0)      = o1;
        *(f16x8*)(kr + ob + 64 + d0) = o2;
    } else {                                // V transpose via LDS 64x128 tile
        __shared__ f16 T[64][132];          // pad 128->132: dword stride 66 -> 2-way (free)
        int vb = blk - 2560;                // 0..255
        int st = vb & 15;
        int hk = (vb >> 4) & 7;
        int b  = vb >> 7;
        int r  = t >> 2, cg = (t & 3) * 32;
        const f16* src = qkv + (size_t)(b * S_ + st*64 + r) * istr + (size_t)(D_ + KV_) + hk*HD_ + cg;
        #pragma unroll
        for (int k = 0; k < 4; ++k)
            *(f16x8*)&T[r][cg + k*8] = *(const f16x8*)(src + k*8);
        __syncthreads();
        int d = t >> 1, sg = (t & 1) * 32;
        f16* dst = vtr + ((size_t)(b * HK_ + hk) * HD_ + d) * S_ + st*64 + sg;
        #pragma unroll
        for (int k = 0; k < 4; ++k){
            f16x8 v;
            #pragma unroll
            for (int j = 0; j < 8; ++j) v[j] = T[sg + k*8 + j][d];
            *(f16x8*)(dst + k*8) = v;
        }
    }
}

// ---------------- fused flash attention ----------------
__global__ __launch_bounds__(256) void k_flash(const f16* __restrict__ Qr, const f16* __restrict__ Kr,
        const f16* __restrict__ Vt, const float* __restrict__ mAddG, f16* __restrict__ ctx)
{
    __shared__ f16 KS[8192];
    __shared__ f16 VS[8192];
    __shared__ f16 PS[8192];
    const int t = threadIdx.x;
    const int w = t >> 6, l = t & 63;
    const int lr = l & 15, lg = l >> 4;
    const int qt = blockIdx.x, bh = blockIdx.y;
    const int b = bh >> 5, hh = bh & 31, hk = hh >> 2;
    const f16* Qb = Qr + ((size_t)bh * S_ + (size_t)qt*128) * HD_;
    const f16* Kb = Kr + (size_t)(b * HK_ + hk) * S_ * HD_;
    const f16* Vb = Vt + (size_t)(b * HK_ + hk) * HD_ * S_;

    auto stage16x128 = [&](const f16* src, int lds_, f16* dst){
        int rowl = t >> 4;
        int cs = ((t & 15) ^ (rowl & 7)) << 3;
        #pragma unroll
        for (int g = 0; g < 4; ++g)
            __builtin_amdgcn_global_load_lds(AS1(src + (size_t)(g*16 + rowl)*lds_ + cs),
                AS3(dst + g*2048 + w*512), 16, 0, 0);
    };
    auto stage32x64 = [&](const f16* src, int lds_, f16* dst){
        int rowl = t >> 3;
        int cs = ((t & 7) ^ (rowl & 7)) << 3;
        #pragma unroll
        for (int g = 0; g < 4; ++g)
            __builtin_amdgcn_global_load_lds(AS1(src + (size_t)(g*32 + rowl)*lds_ + cs),
                AS3(dst + g*2048 + w*512), 16, 0, 0);
    };

    stage16x128(Qb, HD_, KS);
    stage16x128(Qb + 64*HD_, HD_, VS);
    __syncthreads();
    f16x8 qF[2][4];
    {
        const f16* qsrc = (w < 2) ? KS : VS;
        int rbase = (w & 1) * 32;
        #pragma unroll
        for (int m = 0; m < 2; ++m)
            #pragma unroll
            for (int kd = 0; kd < 4; ++kd){
                int row = rbase + m*16 + lr;
                qF[m][kd] = *(const f16x8*)&qsrc[row*128 + (((kd*4 + lg) ^ (row & 7)) << 3)];
            }
    }
    __syncthreads();

    float mrow[2][4], lrow[2][4];
    f32x4 oacc[2][8];
    #pragma unroll
    for (int m = 0; m < 2; ++m)
        #pragma unroll
        for (int r = 0; r < 4; ++r){ mrow[m][r] = -1e30f; lrow[m][r] = 0.f; }
    #pragma unroll
    for (int m = 0; m < 2; ++m)
        #pragma unroll
        for (int dn = 0; dn < 8; ++dn){ f32x4 z = {0,0,0,0}; oacc[m][dn] = z; }

    const float ISQ = 0.08838834764831845f;
    const int ktMax = 2*qt + 1;

    for (int kt = 0; kt <= ktMax; ++kt){
        stage16x128(Kb + (size_t)(kt*64)*HD_, HD_, KS);
        __syncthreads();

        f32x4 sacc[2][4];
        #pragma unroll
        for (int m = 0; m < 2; ++m)
            #pragma unroll
            for (int n = 0; n < 4; ++n){ f32x4 z = {0,0,0,0}; sacc[m][n] = z; }
        #pragma unroll
        for (int n = 0; n < 4; ++n){
            int krow = n*16 + lr;
            #pragma unroll
            for (int kd = 0; kd < 4; ++kd){
                f16x8 kF = *(const f16x8*)&KS[krow*128 + (((kd*4 + lg) ^ (krow & 7)) << 3)];
                #pragma unroll
                for (int m = 0; m < 2; ++m)
                    sacc[m][n] = __builtin_amdgcn_mfma_f32_16x16x32_f16(qF[m][kd], kF, sacc[m][n], 0, 0, 0);
            }
        }

        stage32x64(Vb + kt*64, S_, VS);

        float mAdd[4];
        #pragma unroll
        for (int n = 0; n < 4; ++n) mAdd[n] = mAddG[b*S_ + kt*64 + n*16 + lr];
        int diag = (kt >= 2*qt);
        #pragma unroll
        for (int m = 0; m < 2; ++m)
        #pragma unroll
        for (int n = 0; n < 4; ++n)
        #pragma unroll
        for (int r = 0; r < 4; ++r){
            float s = sacc[m][n][r] * ISQ + mAdd[n];
            if (diag && (kt*64 + n*16 + lr) > (qt*128 + w*32 + m*16 + lg*4 + r)) s = -1e30f;
            sacc[m][n][r] = s;
        }
        #pragma unroll
        for (int m = 0; m < 2; ++m)
        #pragma unroll
        for (int r = 0; r < 4; ++r){
            float tm = fmaxf(fmaxf(sacc[m][0][r], sacc[m][1][r]), fmaxf(sacc[m][2][r], sacc[m][3][r]));
            #pragma unroll
            for (int msk = 1; msk < 16; msk <<= 1) tm = fmaxf(tm, __shfl_xor(tm, msk, 64));
            float mn = fmaxf(mrow[m][r], tm);
            float scl = __expf(mrow[m][r] - mn);
            mrow[m][r] = mn;
            float rs = 0.f;
            #pragma unroll
            for (int n = 0; n < 4; ++n){
                float p = __expf(sacc[m][n][r] - mn);
                sacc[m][n][r] = p; rs += p;
            }
            #pragma unroll
            for (int msk = 1; msk < 16; msk <<= 1) rs += __shfl_xor(rs, msk, 64);
            lrow[m][r] = lrow[m][r] * scl + rs;
            #pragma unroll
            for (int dn = 0; dn < 8; ++dn) oacc[m][dn][r] *= scl;
        }
        #pragma unroll
        for (int m = 0; m < 2; ++m)
        #pragma unroll
        for (int n = 0; n < 4; ++n)
        #pragma unroll
        for (int r = 0; r < 4; ++r){
            int rowl = m*16 + lg*4 + r;
            int slot = (n*2 + (lr >> 3)) ^ (rowl & 7);
            PS[w*2048 + rowl*64 + slot*8 + (lr & 7)] = (f16)sacc[m][n][r];
        }
        __syncthreads();

        f16x8 pF[2][2];
        #pragma unroll
        for (int m = 0; m < 2; ++m)
            #pragma unroll
            for (int kd = 0; kd < 2; ++kd){
                int prow = m*16 + lr;
                pF[m][kd] = *(const f16x8*)&PS[w*2048 + prow*64 + (((kd*4 + lg) ^ (prow & 7)) << 3)];
            }
        #pragma unroll
        for (int dn = 0; dn < 8; ++dn){
            int vrow = dn*16 + lr;
            #pragma unroll
            for (int kd = 0; kd < 2; ++kd){
                f16x8 vF = *(const f16x8*)&VS[vrow*64 + (((kd*4 + lg) ^ (vrow & 7)) << 3)];
                #pragma unroll
                for (int m = 0; m < 2; ++m)
                    oacc[m][dn] = __builtin_amdgcn_mfma_f32_16x16x32_f16(pF[m][kd], vF, oacc[m][dn], 0, 0, 0);
            }
        }
        __syncthreads();
    }

    #pragma unroll
    for (int m = 0; m < 2; ++m)
    #pragma unroll
    for (int dn = 0; dn < 8; ++dn)
    #pragma unroll
    for (int r = 0; r < 4; ++r){
        int grow = qt*128 + w*32 + m*16 + lg*4 + r;
        int gcol = hh*128 + dn*16 + lr;
        float v = oacc[m][dn][r] / fmaxf(lrow[m][r], 1e-30f);
        ctx[((size_t)(b * S_) + grow) * D_ + gcol] = (f16)v;
    }
}

// ---------------- 256x256 8-phase pipelined GEMM (T2+T3+T4+T5, 16x16x32) ----------------
template<int OUT>
__global__ __launch_bounds__(512, 1) void k_gemm3(const f16* __restrict__ A, const f16* __restrict__ Bp,
        void* __restrict__ Cv, const f16* __restrict__ G, int Kd, int ldk, int ldc)
{
    __shared__ f16 LDS[65536];
    const int t = threadIdx.x;
    const int w = t >> 6, l = t & 63;
    const int wm = w >> 2, wn = w & 3;

    int gx = gridDim.x, gy = gridDim.y;
    int nWG = gx * gy * gridDim.z;
    int n = (blockIdx.z * gy + blockIdx.y) * gx + blockIdx.x;
    int q = nWG >> 3;
    int sw = (n & 7) * q + (n >> 3);
    int by = sw % gy; int r1 = sw / gy; int bx = r1 % gx; int bz = r1 / gx;

    const int row0 = by * 256, col0 = bx * 256;
    const size_t koff = (size_t)bz * Kd;
    const int NT = Kd >> 6;

    const int swzk = ((t & 7) ^ ((t >> 3) & 7)) * 8;
    const f16* pA[2]; const f16* pB[2];
    #pragma unroll
    for (int l2 = 0; l2 < 2; ++l2){
        pA[l2] = A  + (size_t)(row0 + l2*128 + (t >> 3)) * ldk + koff + swzk;
        int wnc = (l2*64 + (t >> 3)) >> 5;
        pB[l2] = Bp + (size_t)(col0 + wnc*64 + ((t >> 3) & 31)) * ldk + koff + swzk;
    }

    auto stA = [&](int g, int tt, int buf){
        size_t so = (size_t)tt * 64;
        #pragma unroll
        for (int l2 = 0; l2 < 2; ++l2)
            __builtin_amdgcn_global_load_lds(AS1(pA[l2] + (size_t)g*64*ldk + so),
                AS3(&LDS[buf*16384 + g*8192 + l2*4096 + w*512]), 16, 0, 0);
    };
    auto stB = [&](int g, int tt, int buf){
        size_t so = (size_t)tt * 64;
        #pragma unroll
        for (int l2 = 0; l2 < 2; ++l2)
            __builtin_amdgcn_global_load_lds(AS1(pB[l2] + (size_t)g*32*ldk + so),
                AS3(&LDS[32768 + buf*16384 + g*8192 + l2*4096 + w*512]), 16, 0, 0);
    };

    const int lrow = (l & 15) * 64;
    const int kp0 = (((l >> 4))     ^ (l & 7)) * 8;
    const int kp1 = ((4 + (l >> 4)) ^ (l & 7)) * 8;

    f16x8 aR[2][4], bR0[2][2], bR1[2][2];
    auto rdA = [&](int g, int buf){
        int base = buf*16384 + g*8192 + wm*4096 + lrow;
        #pragma unroll
        for (int mf = 0; mf < 4; ++mf){
            aR[0][mf] = *(const f16x8*)&LDS[base + mf*1024 + kp0];
            aR[1][mf] = *(const f16x8*)&LDS[base + mf*1024 + kp1];
        }
    };
    auto rdB = [&](int g, int buf, f16x8 (&bR)[2][2]){
        int base = 32768 + buf*16384 + g*8192 + wn*2048 + lrow;
        #pragma unroll
        for (int nf = 0; nf < 2; ++nf){
            bR[0][nf] = *(const f16x8*)&LDS[base + nf*1024 + kp0];
            bR[1][nf] = *(const f16x8*)&LDS[base + nf*1024 + kp1];
        }
    };

    f32x4 zero = {0.f, 0.f, 0.f, 0.f};
    f32x4 acc[8][4];
    #pragma unroll
    for (int mi = 0; mi < 8; ++mi)
        #pragma unroll
        for (int ni = 0; ni < 4; ++ni) acc[mi][ni] = zero;

    #define MMQ(qm, qn, bR) { \
        __builtin_amdgcn_s_setprio(1); \
        _Pragma("unroll") \
        for (int ks = 0; ks < 2; ++ks) \
            _Pragma("unroll") \
            for (int mf = 0; mf < 4; ++mf) \
                _Pragma("unroll") \
                for (int nf = 0; nf < 2; ++nf) \
                    acc[(qm)*4+mf][(qn)*2+nf] = __builtin_amdgcn_mfma_f32_16x16x32_f16(aR[ks][mf], bR[ks][nf], acc[(qm)*4+mf][(qn)*2+nf], 0, 0, 0); \
        __builtin_amdgcn_s_setprio(0); }
    #define LGKM0 { asm volatile("s_waitcnt lgkmcnt(0)" ::: "memory"); __builtin_amdgcn_sched_barrier(0); }
    #define VM4   { asm volatile("s_waitcnt vmcnt(4)" ::: "memory"); }
    #define BAR   __builtin_amdgcn_s_barrier()

    stA(0, 0, 0); stB(1, 0, 0); stA(1, 0, 0); stB(0, 0, 0);
    if (NT > 1){ stA(0, 1, 1); stB(1, 1, 1); }
    VM4; BAR;

    for (int tt = 0; tt < NT; tt += 2){
        int c2 = (tt + 2 < NT) ? tt + 2 : NT - 1;
        int c3 = (tt + 3 < NT) ? tt + 3 : NT - 1;
        rdA(0, 0); rdB(0, 0, bR0);
        stA(1, tt+1 < NT ? tt+1 : NT-1, 1); stB(0, tt+1 < NT ? tt+1 : NT-1, 1);
        BAR; LGKM0; MMQ(0, 0, bR0); BAR;
        rdB(1, 0, bR1);
        BAR; LGKM0; MMQ(0, 1, bR1); BAR;
        rdA(1, 0);
        stA(0, c2, 0);
        BAR; LGKM0; MMQ(1, 1, bR1); BAR;
        stB(1, c2, 0);
        BAR; MMQ(1, 0, bR0); VM4; BAR;
        rdA(0, 1); rdB(0, 1, bR0);
        stA(1, c2, 0); stB(0, c2, 0);
        BAR; LGKM0; MMQ(0, 0, bR0); BAR;
        rdB(1, 1, bR1);
        BAR; LGKM0; MMQ(0, 1, bR1); BAR;
        rdA(1, 1);
        stA(0, c3, 1);
        BAR; LGKM0; MMQ(1, 1, bR1); BAR;
        stB(1, c3, 1);
        BAR; MMQ(1, 0, bR0); VM4; BAR;
    }

    #pragma unroll
    for (int mi = 0; mi < 8; ++mi)
    #pragma unroll
    for (int ni = 0; ni < 4; ++ni)
    #pragma unroll
    for (int r = 0; r < 4; ++r){
        int row = row0 + wm*128 + mi*16 + ((l >> 4) << 2) + r;
        int col = col0 + wn*64  + ni*16 + (l & 15);
        float v = acc[mi][ni][r];
        if (OUT == 0){
            ((float*)Cv)[(size_t)bz * ((size_t)M_ * ldc) + (size_t)row * ldc + col] = v;
        } else if (OUT == 2){
            ((f16*)Cv)[(size_t)row * ldc + col] = (f16)v;
        } else {
            size_t idx = (size_t)row * ldc + col;
            float g = (float)G[idx];
            float sg = g / (1.f + __expf(-g));
            ((f16*)Cv)[idx] = (f16)(sg * v);
        }
    }
    #undef MMQ
    #undef LGKM0
    #undef VM4
    #undef BAR
}

// ---------------- masked mean pool, 2-stage ----------------
__global__ __launch_bounds__(256) void k_pool1(const float* __restrict__ Hn, const int* __restrict__ amask,
        float* __restrict__ part, float* __restrict__ cntp)
{
    int d0 = blockIdx.x * 256 + threadIdx.x;
    int b  = blockIdx.y;
    int z  = blockIdx.z;
    int s0 = z * 128;
    float s = 0.f;
    for (int i = 0; i < 128; ++i){
        int row = s0 + i;
        if (amask[b * S_ + row])
            s += Hn[((size_t)(b * S_ + row)) * D_ + d0];
    }
    part[((size_t)(z * B_ + b)) * D_ + d0] = s;
    if (blockIdx.x == 0 && threadIdx.x == 0){
        float c = 0.f;
        for (int i = 0; i < 128; ++i) c += (amask[b * S_ + s0 + i] != 0) ? 1.f : 0.f;
        cntp[z * B_ + b] = c;
    }
}
__global__ __launch_bounds__(256) void k_pool2(const float* __restrict__ part, const float* __restrict__ cntp,
        float* __restrict__ outp)
{
    int gid = blockIdx.x * 256 + threadIdx.x;
    int b = gid >> 12, d = gid & (D_ - 1);
    float s = 0.f, c = 0.f;
    #pragma unroll
    for (int z = 0; z < 8; ++z){
        s += part[((size_t)(z * B_ + b)) * D_ + d];
        c += cntp[z * B_ + b];
    }
    outp[gid] = s / fmaxf(c, 1e-9f);
}

// ---------------- launch ----------------
extern "C" void kernel_launch(void* const* d_in, const int* in_sizes, int n_in,
                              void* d_out, int out_size, void* d_ws, size_t ws_size,
                              hipStream_t stream)
{
    (void)in_sizes; (void)n_in; (void)out_size; (void)ws_size;
    const int*   ids   = (const int*)  d_in[0];
    const int*   amask = (const int*)  d_in[1];
    const float* embed = (const float*)d_in[2];
    const void*  qi = d_in[3];  const float* qa = (const float*)d_in[4];
    const void*  ki = d_in[5];  const float* ka = (const float*)d_in[6];
    const void*  vi = d_in[7];  const float* va = (const float*)d_in[8];
    const void*  oi = d_in[9];  const float* oa = (const float*)d_in[10];
    const void*  gi = d_in[11]; const float* ga = (const float*)d_in[12];
    const void*  ui = d_in[13]; const float* ua = (const float*)d_in[14];
    const void*  di = d_in[15]; const float* da = (const float*)d_in[16];
    const float* ln1 = (const float*)d_in[17];
    const float* ln2 = (const float*)d_in[18];
    const float* lnf = (const float*)d_in[19];

    char* ws = (char*)d_ws;
    int*   flag = (int*)ws;
    float* h    = (float*)(ws + 256);
    float* cosT = (float*)(ws + 256 + 33554432);
    float* sinT = cosT + 65536;
    f16*   xin  = (f16*)(ws + 34078976);
    char*  R4   = ws + 168296704;
    f16* qkv16 = (f16*)(R4);
    f16* qr  = (f16*)(R4 + 25165824);
    f16* kr  = (f16*)(R4 + 41943040);
    f16* vtr = (f16*)(R4 + 46137344);
    f16* ctx = (f16*)(R4 + 50331648);
    char* R5 = R4 + 67108864;
    f16*    gbuf   = (f16*)R5;
    float*  pR5_0  = (float*)R5;
    float*  pR5_1  = (float*)(R5 + 33554432);
    float*  pR4_0  = (float*)R4;
    float*  pR4_1  = (float*)(R4 + 33554432);
    float*  hn     = (float*)R4;
    float*  part   = (float*)R5;
    float*  cntp   = (float*)(R5 + 1048576);
    float*  maskAdd= (float*)(ws + 310378496);
    f16*    wc     = (f16*)(ws + 335544320);   // 872.4 MB weight cache (both layers)

    const int QKV_N = D_ + 2 * KV_;

    k_detect <<<1, 64, 0, stream>>>((const unsigned*)qi, flag);
    k_dequant_all<<<2*106496, 256, 0, stream>>>(qi, ki, vi, oi, gi, ui, di,
            qa, ka, va, oa, ga, ua, da, wc, flag);
    k_embed  <<<M_, 256, 0, stream>>>(ids, embed, h);
    k_ropetab<<<256, 256, 0, stream>>>(cosT, sinT);
    k_maskadd<<<(B_*S_)/256, 256, 0, stream>>>(amask, maskAdd);
    k_rmsnorm<1><<<M_, 256, 0, stream>>>(h, ln1, xin);      // layer-0 input norm

    for (int l = 0; l < 2; ++l){
        f16* wcl = wc + (size_t)l * WC_LAYER;

        // QKV projection from weight cache
        k_gemm3<2><<<dim3(QKV_N/256, M_/256, 1), 512, 0, stream>>>(xin, wcl, qkv16, nullptr, D_, D_, QKV_N);
        k_qkvprep<<<2816, 256, 0, stream>>>(qkv16, qr, kr, vtr, cosT, sinT);

        // fused flash attention
        k_flash<<<dim3(S_/128, B_*H_), 256, 0, stream>>>(qr, kr, vtr, maskAdd, ctx);

        // O projection (split-K x2) + fused residual + ln2 norm
        k_gemm3<0><<<dim3(D_/256, M_/256, 2), 512, 0, stream>>>(ctx, wcl + WC_O, pR5_0, nullptr, D_/2, D_, D_);
        k_combnorm<1><<<M_, 256, 0, stream>>>(h, pR5_0, pR5_1, ln2 + l * D_, xin);

        // MLP from weight cache
        k_gemm3<2><<<dim3(F_/256, M_/256, 1), 512, 0, stream>>>(xin, wcl + WC_G, gbuf, nullptr, D_, D_, F_);
        k_gemm3<3><<<dim3(F_/256, M_/256, 1), 512, 0, stream>>>(xin, wcl + WC_U, gbuf, gbuf, D_, D_, F_);
        k_gemm3<0><<<dim3(D_/256, M_/256, 2), 512, 0, stream>>>(gbuf, wcl + WC_D, pR4_0, nullptr, F_/2, F_, D_);

        // down combine + residual + next-input norm (ln1[1] for l=0, final lnf for l=1)
        if (l == 0)
            k_combnorm<1><<<M_, 256, 0, stream>>>(h, pR4_0, pR4_1, ln1 + D_, xin);
        else
            k_combnorm<0><<<M_, 256, 0, stream>>>(h, pR4_0, pR4_1, lnf, hn);
    }

    k_pool1<<<dim3(D_/256, B_, 8), 256, 0, stream>>>(hn, amask, part, cntp);
    k_pool2<<<(B_*D_)/256, 256, 0, stream>>>(part, cntp, (float*)d_out);
}

// Round 18
// 2407.429 us; speedup vs baseline: 2.1951x; 1.0062x over previous
//
#include <hip/hip_runtime.h>
#include <hip/hip_fp16.h>
#include <cstdint>
#include <cstddef>

// ---------------- problem constants ----------------
#define B_  2
#define S_  1024
#define D_  4096
#define KV_ 1024
#define F_  14336
#define H_  32
#define HK_ 8
#define HD_ 128
#define M_  2048   // B*S

typedef _Float16 f16;
typedef f16   f16x8 __attribute__((ext_vector_type(8)));
typedef f16   f16x4 __attribute__((ext_vector_type(4)));
typedef float f32x4 __attribute__((ext_vector_type(4)));
typedef unsigned u32x2 __attribute__((ext_vector_type(2)));
typedef unsigned u32x4 __attribute__((ext_vector_type(4)));
typedef int      i32x4 __attribute__((ext_vector_type(4)));

#define AS1(p) ((const __attribute__((address_space(1))) void*)(p))
#define AS3(p) ((__attribute__((address_space(3))) void*)(p))

__device__ __constant__ float NF4_C[16] = {
 -1.0f, -0.6961928009986877f, -0.5250730514526367f, -0.39491748809814453f,
 -0.28444138169288635f, -0.18477343022823334f, -0.09105003625154495f, 0.0f,
 0.07958029955625534f, 0.16093020141124725f, 0.24611230194568634f,
 0.33791524171829224f, 0.44070982933044434f, 0.5626170039176941f,
 0.7229568362236023f, 1.0f };

// per-layer f16 weight-cache element offsets
#define WC_LAYER  218103808ull     // elems per layer
#define WC_O      25165824ull
#define WC_G      41943040ull
#define WC_U      100663296ull
#define WC_D      159383552ull

// ---------------- dtype detection (u8 vs i32 idx arrays) ----------------
__global__ void k_detect(const unsigned* __restrict__ p, int* __restrict__ flag){
    if (threadIdx.x == 0){
        int u8 = 0;
        for (int i = 0; i < 256; ++i) if (p[i] >= 16u) { u8 = 1; break; }
        *flag = u8;
    }
}

// ---------------- mega-dequant v2: 8 elems/thread, full-line stores ----------------
__global__ __launch_bounds__(256) void k_dequant_all(
        const void* __restrict__ qi, const void* __restrict__ ki, const void* __restrict__ vi,
        const void* __restrict__ oi, const void* __restrict__ gi, const void* __restrict__ ui,
        const void* __restrict__ di,
        const float* __restrict__ qa, const float* __restrict__ ka, const float* __restrict__ va,
        const float* __restrict__ oa, const float* __restrict__ ga, const float* __restrict__ ua,
        const float* __restrict__ da,
        f16* __restrict__ wc, const int* __restrict__ flag)
{
    __shared__ __half2 T[3856];
    int t = threadIdx.x;
    if (t < 256){
        int b0 = t & 15, b1 = t >> 4;
        T[b0 + (b1 << 8)] = __halves2half2(__float2half(NF4_C[b0]), __float2half(NF4_C[b1]));
    }
    __syncthreads();
    int blk = blockIdx.x;
    int l = blk / 106496; blk -= l * 106496;
    const size_t DDc = (size_t)D_ * D_, KVDc = (size_t)KV_ * D_, FDc = (size_t)F_ * D_;
    size_t oDD = (size_t)l * DDc, oKVD = (size_t)l * KVDc, oFD = (size_t)l * FDc;
    f16* wl = wc + (size_t)l * WC_LAYER;
    const void* src; const float* am; size_t so; f16* dst;
    if (blk < 8192)       { src = qi; am = qa; so = oDD;  dst = wl; }
    else if (blk < 10240) { src = ki; am = ka; so = oKVD; dst = wl + DDc;        blk -= 8192; }
    else if (blk < 12288) { src = vi; am = va; so = oKVD; dst = wl + DDc + KVDc; blk -= 10240; }
    else if (blk < 20480) { src = oi; am = oa; so = oDD;  dst = wl + WC_O;       blk -= 12288; }
    else if (blk < 49152) { src = gi; am = ga; so = oFD;  dst = wl + WC_G;       blk -= 20480; }
    else if (blk < 77824) { src = ui; am = ua; so = oFD;  dst = wl + WC_U;       blk -= 49152; }
    else                  { src = di; am = da; so = oFD;  dst = wl + WC_D;       blk -= 77824; }
    size_t i = ((size_t)blk * 256 + t) * 8;          // 8 elems per thread
    float amv = am[(so + i) >> 6];
    __half2 am2 = __float2half2_rn(amv);
    union { __half2 h2[4]; u32x4 u4; } R;
    if (*flag){
        u32x2 u = *(const u32x2*)((const uint8_t*)src + so + i);
        R.h2[0] = __hmul2(T[u.x & 0xFFFFu], am2);
        R.h2[1] = __hmul2(T[u.x >> 16],     am2);
        R.h2[2] = __hmul2(T[u.y & 0xFFFFu], am2);
        R.h2[3] = __hmul2(T[u.y >> 16],     am2);
    } else {
        const i32x4* s4 = (const i32x4*)((const int*)src + so + i);
        i32x4 a0 = s4[0], a1 = s4[1];
        R.h2[0] = __hmul2(T[a0.x | (a0.y << 8)], am2);
        R.h2[1] = __hmul2(T[a0.z | (a0.w << 8)], am2);
        R.h2[2] = __hmul2(T[a1.x | (a1.y << 8)], am2);
        R.h2[3] = __hmul2(T[a1.z | (a1.w << 8)], am2);
    }
    *(u32x4*)(dst + i) = R.u4;
}

// ---------------- RoPE tables + additive mask (merged one-time prep) ----------------
__global__ __launch_bounds__(256) void k_prep(float* __restrict__ cosT, float* __restrict__ sinT,
        const int* __restrict__ am, float* __restrict__ ma)
{
    int blk = blockIdx.x, t = threadIdx.x;
    if (blk < 256){
        int id = blk * 256 + t;
        int d = id & 63, s = id >> 6;
        float inv = powf(500000.0f, -(float)d * (1.0f/64.0f));
        float ang = (float)s * inv;
        cosT[id] = cosf(ang);
        sinT[id] = sinf(ang);
    } else {
        int i = (blk - 256) * 256 + t;
        ma[i] = am[i] ? 0.f : -1e30f;
    }
}

// ---------------- fused embedding gather + layer-0 RMSNorm ----------------
__global__ __launch_bounds__(256) void k_embednorm(const int* __restrict__ ids,
        const float* __restrict__ E, const float* __restrict__ W,
        float* __restrict__ Hh, f16* __restrict__ xout)
{
    int row = blockIdx.x, t = threadIdx.x;
    int id = ids[row];
    const float4* s4 = (const float4*)(E + (size_t)id * D_);
    float4* d4 = (float4*)(Hh + (size_t)row * D_);
    float4 xs[4]; float ss = 0.f;
    #pragma unroll
    for (int i = 0; i < 4; ++i){
        xs[i] = s4[t + 256*i];
        d4[t + 256*i] = xs[i];
        ss += xs[i].x*xs[i].x + xs[i].y*xs[i].y + xs[i].z*xs[i].z + xs[i].w*xs[i].w;
    }
    for (int m = 32; m; m >>= 1) ss += __shfl_xor(ss, m, 64);
    __shared__ float red[4];
    if ((t & 63) == 0) red[t >> 6] = ss;
    __syncthreads();
    ss = red[0] + red[1] + red[2] + red[3];
    float rs = rsqrtf(ss * (1.0f / D_) + 1e-5f);
    #pragma unroll
    for (int i = 0; i < 4; ++i){
        int c0 = (t + 256*i) * 4;
        float4 wv = *(const float4*)(W + c0);
        f16x4 ov = { (f16)(xs[i].x*rs*wv.x), (f16)(xs[i].y*rs*wv.y),
                     (f16)(xs[i].z*rs*wv.z), (f16)(xs[i].w*rs*wv.w) };
        *(f16x4*)(xout + (size_t)row * D_ + c0) = ov;
    }
}

// ---------------- fused split-K combine + residual + RMSNorm ----------------
template<int F16OUT>
__global__ __launch_bounds__(256) void k_combnorm(float* __restrict__ H,
        const float* __restrict__ p0, const float* __restrict__ p1,
        const float* __restrict__ W, void* __restrict__ outv)
{
    int row = blockIdx.x, t = threadIdx.x;
    size_t base = (size_t)row * D_;
    float4 xs[4]; float ss = 0.f;
    #pragma unroll
    for (int i = 0; i < 4; ++i){
        int c4 = (t + 256*i) * 4;
        float4 hv = *(const float4*)(H + base + c4);
        float4 a  = *(const float4*)(p0 + base + c4);
        float4 b  = *(const float4*)(p1 + base + c4);
        hv.x += a.x + b.x; hv.y += a.y + b.y; hv.z += a.z + b.z; hv.w += a.w + b.w;
        *(float4*)(H + base + c4) = hv;
        xs[i] = hv;
        ss += hv.x*hv.x + hv.y*hv.y + hv.z*hv.z + hv.w*hv.w;
    }
    for (int m = 32; m; m >>= 1) ss += __shfl_xor(ss, m, 64);
    __shared__ float red[4];
    if ((t & 63) == 0) red[t >> 6] = ss;
    __syncthreads();
    ss = red[0] + red[1] + red[2] + red[3];
    float rs = rsqrtf(ss * (1.0f / D_) + 1e-5f);
    #pragma unroll
    for (int i = 0; i < 4; ++i){
        int c0 = (t + 256*i) * 4;
        float4 wv = *(const float4*)(W + c0);
        float o0 = xs[i].x*rs*wv.x, o1 = xs[i].y*rs*wv.y;
        float o2 = xs[i].z*rs*wv.z, o3 = xs[i].w*rs*wv.w;
        if (F16OUT){
            f16x4 ov = { (f16)o0, (f16)o1, (f16)o2, (f16)o3 };
            *(f16x4*)((f16*)outv + base + c0) = ov;
        } else {
            float4 ov = {o0, o1, o2, o3};
            *(float4*)((float*)outv + base + c0) = ov;
        }
    }
}

// ---------------- QKV post-proc v2: vectorized rope + LDS-transpose V ----------------
__global__ __launch_bounds__(256) void k_qkvprep(const f16* __restrict__ qkv,
        f16* __restrict__ qr, f16* __restrict__ kr, f16* __restrict__ vtr,
        const float* __restrict__ cosT, const float* __restrict__ sinT)
{
    const int istr = D_ + 2 * KV_;
    int blk = blockIdx.x;
    int t = threadIdx.x;
    if (blk < 2048){                        // rope Q
        int p = blk * 256 + t;
        int d0 = (p & 7) * 8;
        int h  = (p >> 3) & 31;
        int s  = (p >> 8) & (S_ - 1);
        int b  = p >> 18;
        size_t ib = (size_t)(b * S_ + s) * istr + (size_t)h * HD_;
        f16x8 x1 = *(const f16x8*)(qkv + ib + d0);
        f16x8 x2 = *(const f16x8*)(qkv + ib + 64 + d0);
        f32x4 c0 = *(const f32x4*)(cosT + s*64 + d0);
        f32x4 c1 = *(const f32x4*)(cosT + s*64 + d0 + 4);
        f32x4 s0 = *(const f32x4*)(sinT + s*64 + d0);
        f32x4 s1 = *(const f32x4*)(sinT + s*64 + d0 + 4);
        f16x8 o1, o2;
        #pragma unroll
        for (int j = 0; j < 8; ++j){
            float c = (j < 4) ? c0[j] : c1[j-4];
            float sn = (j < 4) ? s0[j] : s1[j-4];
            float a = (float)x1[j], bb = (float)x2[j];
            o1[j] = (f16)(a * c - bb * sn);
            o2[j] = (f16)(bb * c + a * sn);
        }
        size_t ob = (((size_t)((b << 5) + h)) * S_ + (size_t)s) * HD_;
        *(f16x8*)(qr + ob + d0)      = o1;
        *(f16x8*)(qr + ob + 64 + d0) = o2;
    } else if (blk < 2560){                 // rope K
        int p = (blk - 2048) * 256 + t;
        int d0 = (p & 7) * 8;
        int hk = (p >> 3) & 7;
        int s  = (p >> 6) & (S_ - 1);
        int b  = p >> 16;
        size_t ib = (size_t)(b * S_ + s) * istr + (size_t)D_ + (size_t)hk * HD_;
        f16x8 x1 = *(const f16x8*)(qkv + ib + d0);
        f16x8 x2 = *(const f16x8*)(qkv + ib + 64 + d0);
        f32x4 c0 = *(const f32x4*)(cosT + s*64 + d0);
        f32x4 c1 = *(const f32x4*)(cosT + s*64 + d0 + 4);
        f32x4 s0 = *(const f32x4*)(sinT + s*64 + d0);
        f32x4 s1 = *(const f32x4*)(sinT + s*64 + d0 + 4);
        f16x8 o1, o2;
        #pragma unroll
        for (int j = 0; j < 8; ++j){
            float c = (j < 4) ? c0[j] : c1[j-4];
            float sn = (j < 4) ? s0[j] : s1[j-4];
            float a = (float)x1[j], bb = (float)x2[j];
            o1[j] = (f16)(a * c - bb * sn);
            o2[j] = (f16)(bb * c + a * sn);
        }
        size_t ob = (((size_t)((b << 3) + hk)) * S_ + (size_t)s) * HD_;
        *(f16x8*)(kr + ob + d0)      = o1;
        *(f16x8*)(kr + ob + 64 + d0) = o2;
    } else {                                // V transpose via LDS 64x128 tile
        __shared__ f16 T[64][132];
        int vb = blk - 2560;
        int st = vb & 15;
        int hk = (vb >> 4) & 7;
        int b  = vb >> 7;
        int r  = t >> 2, cg = (t & 3) * 32;
        const f16* src = qkv + (size_t)(b * S_ + st*64 + r) * istr + (size_t)(D_ + KV_) + hk*HD_ + cg;
        #pragma unroll
        for (int k = 0; k < 4; ++k)
            *(f16x8*)&T[r][cg + k*8] = *(const f16x8*)(src + k*8);
        __syncthreads();
        int d = t >> 1, sg = (t & 1) * 32;
        f16* dst = vtr + ((size_t)(b * HK_ + hk) * HD_ + d) * S_ + st*64 + sg;
        #pragma unroll
        for (int k = 0; k < 4; ++k){
            f16x8 v;
            #pragma unroll
            for (int j = 0; j < 8; ++j) v[j] = T[sg + k*8 + j][d];
            *(f16x8*)(dst + k*8) = v;
        }
    }
}

// ---------------- fused flash attention ----------------
__global__ __launch_bounds__(256) void k_flash(const f16* __restrict__ Qr, const f16* __restrict__ Kr,
        const f16* __restrict__ Vt, const float* __restrict__ mAddG, f16* __restrict__ ctx)
{
    __shared__ f16 KS[8192];
    __shared__ f16 VS[8192];
    __shared__ f16 PS[8192];
    const int t = threadIdx.x;
    const int w = t >> 6, l = t & 63;
    const int lr = l & 15, lg = l >> 4;
    const int qt = blockIdx.x, bh = blockIdx.y;
    const int b = bh >> 5, hh = bh & 31, hk = hh >> 2;
    const f16* Qb = Qr + ((size_t)bh * S_ + (size_t)qt*128) * HD_;
    const f16* Kb = Kr + (size_t)(b * HK_ + hk) * S_ * HD_;
    const f16* Vb = Vt + (size_t)(b * HK_ + hk) * HD_ * S_;

    auto stage16x128 = [&](const f16* src, int lds_, f16* dst){
        int rowl = t >> 4;
        int cs = ((t & 15) ^ (rowl & 7)) << 3;
        #pragma unroll
        for (int g = 0; g < 4; ++g)
            __builtin_amdgcn_global_load_lds(AS1(src + (size_t)(g*16 + rowl)*lds_ + cs),
                AS3(dst + g*2048 + w*512), 16, 0, 0);
    };
    auto stage32x64 = [&](const f16* src, int lds_, f16* dst){
        int rowl = t >> 3;
        int cs = ((t & 7) ^ (rowl & 7)) << 3;
        #pragma unroll
        for (int g = 0; g < 4; ++g)
            __builtin_amdgcn_global_load_lds(AS1(src + (size_t)(g*32 + rowl)*lds_ + cs),
                AS3(dst + g*2048 + w*512), 16, 0, 0);
    };

    stage16x128(Qb, HD_, KS);
    stage16x128(Qb + 64*HD_, HD_, VS);
    __syncthreads();
    f16x8 qF[2][4];
    {
        const f16* qsrc = (w < 2) ? KS : VS;
        int rbase = (w & 1) * 32;
        #pragma unroll
        for (int m = 0; m < 2; ++m)
            #pragma unroll
            for (int kd = 0; kd < 4; ++kd){
                int row = rbase + m*16 + lr;
                qF[m][kd] = *(const f16x8*)&qsrc[row*128 + (((kd*4 + lg) ^ (row & 7)) << 3)];
            }
    }
    __syncthreads();

    float mrow[2][4], lrow[2][4];
    f32x4 oacc[2][8];
    #pragma unroll
    for (int m = 0; m < 2; ++m)
        #pragma unroll
        for (int r = 0; r < 4; ++r){ mrow[m][r] = -1e30f; lrow[m][r] = 0.f; }
    #pragma unroll
    for (int m = 0; m < 2; ++m)
        #pragma unroll
        for (int dn = 0; dn < 8; ++dn){ f32x4 z = {0,0,0,0}; oacc[m][dn] = z; }

    const float ISQ = 0.08838834764831845f;
    const int ktMax = 2*qt + 1;

    for (int kt = 0; kt <= ktMax; ++kt){
        stage16x128(Kb + (size_t)(kt*64)*HD_, HD_, KS);
        __syncthreads();

        f32x4 sacc[2][4];
        #pragma unroll
        for (int m = 0; m < 2; ++m)
            #pragma unroll
            for (int n = 0; n < 4; ++n){ f32x4 z = {0,0,0,0}; sacc[m][n] = z; }
        #pragma unroll
        for (int n = 0; n < 4; ++n){
            int krow = n*16 + lr;
            #pragma unroll
            for (int kd = 0; kd < 4; ++kd){
                f16x8 kF = *(const f16x8*)&KS[krow*128 + (((kd*4 + lg) ^ (krow & 7)) << 3)];
                #pragma unroll
                for (int m = 0; m < 2; ++m)
                    sacc[m][n] = __builtin_amdgcn_mfma_f32_16x16x32_f16(qF[m][kd], kF, sacc[m][n], 0, 0, 0);
            }
        }

        stage32x64(Vb + kt*64, S_, VS);

        float mAdd[4];
        #pragma unroll
        for (int n = 0; n < 4; ++n) mAdd[n] = mAddG[b*S_ + kt*64 + n*16 + lr];
        int diag = (kt >= 2*qt);
        #pragma unroll
        for (int m = 0; m < 2; ++m)
        #pragma unroll
        for (int n = 0; n < 4; ++n)
        #pragma unroll
        for (int r = 0; r < 4; ++r){
            float s = sacc[m][n][r] * ISQ + mAdd[n];
            if (diag && (kt*64 + n*16 + lr) > (qt*128 + w*32 + m*16 + lg*4 + r)) s = -1e30f;
            sacc[m][n][r] = s;
        }
        #pragma unroll
        for (int m = 0; m < 2; ++m)
        #pragma unroll
        for (int r = 0; r < 4; ++r){
            float tm = fmaxf(fmaxf(sacc[m][0][r], sacc[m][1][r]), fmaxf(sacc[m][2][r], sacc[m][3][r]));
            #pragma unroll
            for (int msk = 1; msk < 16; msk <<= 1) tm = fmaxf(tm, __shfl_xor(tm, msk, 64));
            float mn = fmaxf(mrow[m][r], tm);
            float scl = __expf(mrow[m][r] - mn);
            mrow[m][r] = mn;
            float rs = 0.f;
            #pragma unroll
            for (int n = 0; n < 4; ++n){
                float p = __expf(sacc[m][n][r] - mn);
                sacc[m][n][r] = p; rs += p;
            }
            #pragma unroll
            for (int msk = 1; msk < 16; msk <<= 1) rs += __shfl_xor(rs, msk, 64);
            lrow[m][r] = lrow[m][r] * scl + rs;
            #pragma unroll
            for (int dn = 0; dn < 8; ++dn) oacc[m][dn][r] *= scl;
        }
        #pragma unroll
        for (int m = 0; m < 2; ++m)
        #pragma unroll
        for (int n = 0; n < 4; ++n)
        #pragma unroll
        for (int r = 0; r < 4; ++r){
            int rowl = m*16 + lg*4 + r;
            int slot = (n*2 + (lr >> 3)) ^ (rowl & 7);
            PS[w*2048 + rowl*64 + slot*8 + (lr & 7)] = (f16)sacc[m][n][r];
        }
        __syncthreads();

        f16x8 pF[2][2];
        #pragma unroll
        for (int m = 0; m < 2; ++m)
            #pragma unroll
            for (int kd = 0; kd < 2; ++kd){
                int prow = m*16 + lr;
                pF[m][kd] = *(const f16x8*)&PS[w*2048 + prow*64 + (((kd*4 + lg) ^ (prow & 7)) << 3)];
            }
        #pragma unroll
        for (int dn = 0; dn < 8; ++dn){
            int vrow = dn*16 + lr;
            #pragma unroll
            for (int kd = 0; kd < 2; ++kd){
                f16x8 vF = *(const f16x8*)&VS[vrow*64 + (((kd*4 + lg) ^ (vrow & 7)) << 3)];
                #pragma unroll
                for (int m = 0; m < 2; ++m)
                    oacc[m][dn] = __builtin_amdgcn_mfma_f32_16x16x32_f16(pF[m][kd], vF, oacc[m][dn], 0, 0, 0);
            }
        }
        __syncthreads();
    }

    #pragma unroll
    for (int m = 0; m < 2; ++m)
    #pragma unroll
    for (int dn = 0; dn < 8; ++dn)
    #pragma unroll
    for (int r = 0; r < 4; ++r){
        int grow = qt*128 + w*32 + m*16 + lg*4 + r;
        int gcol = hh*128 + dn*16 + lr;
        float v = oacc[m][dn][r] / fmaxf(lrow[m][r], 1e-30f);
        ctx[((size_t)(b * S_) + grow) * D_ + gcol] = (f16)v;
    }
}

// ---------------- 256x256 8-phase pipelined GEMM (T2+T3+T4+T5, 16x16x32) ----------------
template<int OUT>
__global__ __launch_bounds__(512, 1) void k_gemm3(const f16* __restrict__ A, const f16* __restrict__ Bp,
        void* __restrict__ Cv, const f16* __restrict__ G, int Kd, int ldk, int ldc)
{
    __shared__ f16 LDS[65536];
    const int t = threadIdx.x;
    const int w = t >> 6, l = t & 63;
    const int wm = w >> 2, wn = w & 3;

    int gx = gridDim.x, gy = gridDim.y;
    int nWG = gx * gy * gridDim.z;
    int n = (blockIdx.z * gy + blockIdx.y) * gx + blockIdx.x;
    int q = nWG >> 3;
    int sw = (n & 7) * q + (n >> 3);
    int by = sw % gy; int r1 = sw / gy; int bx = r1 % gx; int bz = r1 / gx;

    const int row0 = by * 256, col0 = bx * 256;
    const size_t koff = (size_t)bz * Kd;
    const int NT = Kd >> 6;

    const int swzk = ((t & 7) ^ ((t >> 3) & 7)) * 8;
    const f16* pA[2]; const f16* pB[2];
    #pragma unroll
    for (int l2 = 0; l2 < 2; ++l2){
        pA[l2] = A  + (size_t)(row0 + l2*128 + (t >> 3)) * ldk + koff + swzk;
        int wnc = (l2*64 + (t >> 3)) >> 5;
        pB[l2] = Bp + (size_t)(col0 + wnc*64 + ((t >> 3) & 31)) * ldk + koff + swzk;
    }

    auto stA = [&](int g, int tt, int buf){
        size_t so = (size_t)tt * 64;
        #pragma unroll
        for (int l2 = 0; l2 < 2; ++l2)
            __builtin_amdgcn_global_load_lds(AS1(pA[l2] + (size_t)g*64*ldk + so),
                AS3(&LDS[buf*16384 + g*8192 + l2*4096 + w*512]), 16, 0, 0);
    };
    auto stB = [&](int g, int tt, int buf){
        size_t so = (size_t)tt * 64;
        #pragma unroll
        for (int l2 = 0; l2 < 2; ++l2)
            __builtin_amdgcn_global_load_lds(AS1(pB[l2] + (size_t)g*32*ldk + so),
                AS3(&LDS[32768 + buf*16384 + g*8192 + l2*4096 + w*512]), 16, 0, 0);
    };

    const int lrow = (l & 15) * 64;
    const int kp0 = (((l >> 4))     ^ (l & 7)) * 8;
    const int kp1 = ((4 + (l >> 4)) ^ (l & 7)) * 8;

    f16x8 aR[2][4], bR0[2][2], bR1[2][2];
    auto rdA = [&](int g, int buf){
        int base = buf*16384 + g*8192 + wm*4096 + lrow;
        #pragma unroll
        for (int mf = 0; mf < 4; ++mf){
            aR[0][mf] = *(const f16x8*)&LDS[base + mf*1024 + kp0];
            aR[1][mf] = *(const f16x8*)&LDS[base + mf*1024 + kp1];
        }
    };
    auto rdB = [&](int g, int buf, f16x8 (&bR)[2][2]){
        int base = 32768 + buf*16384 + g*8192 + wn*2048 + lrow;
        #pragma unroll
        for (int nf = 0; nf < 2; ++nf){
            bR[0][nf] = *(const f16x8*)&LDS[base + nf*1024 + kp0];
            bR[1][nf] = *(const f16x8*)&LDS[base + nf*1024 + kp1];
        }
    };

    f32x4 zero = {0.f, 0.f, 0.f, 0.f};
    f32x4 acc[8][4];
    #pragma unroll
    for (int mi = 0; mi < 8; ++mi)
        #pragma unroll
        for (int ni = 0; ni < 4; ++ni) acc[mi][ni] = zero;

    #define MMQ(qm, qn, bR) { \
        __builtin_amdgcn_s_setprio(1); \
        _Pragma("unroll") \
        for (int ks = 0; ks < 2; ++ks) \
            _Pragma("unroll") \
            for (int mf = 0; mf < 4; ++mf) \
                _Pragma("unroll") \
                for (int nf = 0; nf < 2; ++nf) \
                    acc[(qm)*4+mf][(qn)*2+nf] = __builtin_amdgcn_mfma_f32_16x16x32_f16(aR[ks][mf], bR[ks][nf], acc[(qm)*4+mf][(qn)*2+nf], 0, 0, 0); \
        __builtin_amdgcn_s_setprio(0); }
    #define LGKM0 { asm volatile("s_waitcnt lgkmcnt(0)" ::: "memory"); __builtin_amdgcn_sched_barrier(0); }
    #define VM4   { asm volatile("s_waitcnt vmcnt(4)" ::: "memory"); }
    #define BAR   __builtin_amdgcn_s_barrier()

    stA(0, 0, 0); stB(1, 0, 0); stA(1, 0, 0); stB(0, 0, 0);
    if (NT > 1){ stA(0, 1, 1); stB(1, 1, 1); }
    VM4; BAR;

    for (int tt = 0; tt < NT; tt += 2){
        int c2 = (tt + 2 < NT) ? tt + 2 : NT - 1;
        int c3 = (tt + 3 < NT) ? tt + 3 : NT - 1;
        rdA(0, 0); rdB(0, 0, bR0);
        stA(1, tt+1 < NT ? tt+1 : NT-1, 1); stB(0, tt+1 < NT ? tt+1 : NT-1, 1);
        BAR; LGKM0; MMQ(0, 0, bR0); BAR;
        rdB(1, 0, bR1);
        BAR; LGKM0; MMQ(0, 1, bR1); BAR;
        rdA(1, 0);
        stA(0, c2, 0);
        BAR; LGKM0; MMQ(1, 1, bR1); BAR;
        stB(1, c2, 0);
        BAR; MMQ(1, 0, bR0); VM4; BAR;
        rdA(0, 1); rdB(0, 1, bR0);
        stA(1, c2, 0); stB(0, c2, 0);
        BAR; LGKM0; MMQ(0, 0, bR0); BAR;
        rdB(1, 1, bR1);
        BAR; LGKM0; MMQ(0, 1, bR1); BAR;
        rdA(1, 1);
        stA(0, c3, 1);
        BAR; LGKM0; MMQ(1, 1, bR1); BAR;
        stB(1, c3, 1);
        BAR; MMQ(1, 0, bR0); VM4; BAR;
    }

    #pragma unroll
    for (int mi = 0; mi < 8; ++mi)
    #pragma unroll
    for (int ni = 0; ni < 4; ++ni)
    #pragma unroll
    for (int r = 0; r < 4; ++r){
        int row = row0 + wm*128 + mi*16 + ((l >> 4) << 2) + r;
        int col = col0 + wn*64  + ni*16 + (l & 15);
        float v = acc[mi][ni][r];
        if (OUT == 0){
            ((float*)Cv)[(size_t)bz * ((size_t)M_ * ldc) + (size_t)row * ldc + col] = v;
        } else if (OUT == 2){
            ((f16*)Cv)[(size_t)row * ldc + col] = (f16)v;
        } else {
            size_t idx = (size_t)row * ldc + col;
            float g = (float)G[idx];
            float sg = g / (1.f + __expf(-g));
            ((f16*)Cv)[idx] = (f16)(sg * v);
        }
    }
    #undef MMQ
    #undef LGKM0
    #undef VM4
    #undef BAR
}

// ---------------- masked mean pool, 2-stage ----------------
__global__ __launch_bounds__(256) void k_pool1(const float* __restrict__ Hn, const int* __restrict__ amask,
        float* __restrict__ part, float* __restrict__ cntp)
{
    int d0 = blockIdx.x * 256 + threadIdx.x;
    int b  = blockIdx.y;
    int z  = blockIdx.z;
    int s0 = z * 128;
    float s = 0.f;
    for (int i = 0; i < 128; ++i){
        int row = s0 + i;
        if (amask[b * S_ + row])
            s += Hn[((size_t)(b * S_ + row)) * D_ + d0];
    }
    part[((size_t)(z * B_ + b)) * D_ + d0] = s;
    if (blockIdx.x == 0 && threadIdx.x == 0){
        float c = 0.f;
        for (int i = 0; i < 128; ++i) c += (amask[b * S_ + s0 + i] != 0) ? 1.f : 0.f;
        cntp[z * B_ + b] = c;
    }
}
__global__ __launch_bounds__(256) void k_pool2(const float* __restrict__ part, const float* __restrict__ cntp,
        float* __restrict__ outp)
{
    int gid = blockIdx.x * 256 + threadIdx.x;
    int b = gid >> 12, d = gid & (D_ - 1);
    float s = 0.f, c = 0.f;
    #pragma unroll
    for (int z = 0; z < 8; ++z){
        s += part[((size_t)(z * B_ + b)) * D_ + d];
        c += cntp[z * B_ + b];
    }
    outp[gid] = s / fmaxf(c, 1e-9f);
}

// ---------------- launch ----------------
extern "C" void kernel_launch(void* const* d_in, const int* in_sizes, int n_in,
                              void* d_out, int out_size, void* d_ws, size_t ws_size,
                              hipStream_t stream)
{
    (void)in_sizes; (void)n_in; (void)out_size; (void)ws_size;
    const int*   ids   = (const int*)  d_in[0];
    const int*   amask = (const int*)  d_in[1];
    const float* embed = (const float*)d_in[2];
    const void*  qi = d_in[3];  const float* qa = (const float*)d_in[4];
    const void*  ki = d_in[5];  const float* ka = (const float*)d_in[6];
    const void*  vi = d_in[7];  const float* va = (const float*)d_in[8];
    const void*  oi = d_in[9];  const float* oa = (const float*)d_in[10];
    const void*  gi = d_in[11]; const float* ga = (const float*)d_in[12];
    const void*  ui = d_in[13]; const float* ua = (const float*)d_in[14];
    const void*  di = d_in[15]; const float* da = (const float*)d_in[16];
    const float* ln1 = (const float*)d_in[17];
    const float* ln2 = (const float*)d_in[18];
    const float* lnf = (const float*)d_in[19];

    char* ws = (char*)d_ws;
    int*   flag = (int*)ws;
    float* h    = (float*)(ws + 256);
    float* cosT = (float*)(ws + 256 + 33554432);
    float* sinT = cosT + 65536;
    f16*   xin  = (f16*)(ws + 34078976);
    char*  R4   = ws + 168296704;
    f16* qkv16 = (f16*)(R4);
    f16* qr  = (f16*)(R4 + 25165824);
    f16* kr  = (f16*)(R4 + 41943040);
    f16* vtr = (f16*)(R4 + 46137344);
    f16* ctx = (f16*)(R4 + 50331648);
    char* R5 = R4 + 67108864;
    f16*    gbuf   = (f16*)R5;
    float*  pR5_0  = (float*)R5;
    float*  pR5_1  = (float*)(R5 + 33554432);
    float*  pR4_0  = (float*)R4;
    float*  pR4_1  = (float*)(R4 + 33554432);
    float*  hn     = (float*)R4;
    float*  part   = (float*)R5;
    float*  cntp   = (float*)(R5 + 1048576);
    float*  maskAdd= (float*)(ws + 310378496);
    f16*    wc     = (f16*)(ws + 335544320);   // 872.4 MB weight cache (both layers)

    const int QKV_N = D_ + 2 * KV_;

    k_detect <<<1, 64, 0, stream>>>((const unsigned*)qi, flag);
    k_dequant_all<<<2*106496, 256, 0, stream>>>(qi, ki, vi, oi, gi, ui, di,
            qa, ka, va, oa, ga, ua, da, wc, flag);
    k_prep<<<264, 256, 0, stream>>>(cosT, sinT, amask, maskAdd);
    k_embednorm<<<M_, 256, 0, stream>>>(ids, embed, ln1, h, xin);

    for (int l = 0; l < 2; ++l){
        f16* wcl = wc + (size_t)l * WC_LAYER;

        // QKV projection from weight cache
        k_gemm3<2><<<dim3(QKV_N/256, M_/256, 1), 512, 0, stream>>>(xin, wcl, qkv16, nullptr, D_, D_, QKV_N);
        k_qkvprep<<<2816, 256, 0, stream>>>(qkv16, qr, kr, vtr, cosT, sinT);

        // fused flash attention
        k_flash<<<dim3(S_/128, B_*H_), 256, 0, stream>>>(qr, kr, vtr, maskAdd, ctx);

        // O projection (split-K x2) + fused residual + ln2 norm
        k_gemm3<0><<<dim3(D_/256, M_/256, 2), 512, 0, stream>>>(ctx, wcl + WC_O, pR5_0, nullptr, D_/2, D_, D_);
        k_combnorm<1><<<M_, 256, 0, stream>>>(h, pR5_0, pR5_1, ln2 + l * D_, xin);

        // MLP from weight cache
        k_gemm3<2><<<dim3(F_/256, M_/256, 1), 512, 0, stream>>>(xin, wcl + WC_G, gbuf, nullptr, D_, D_, F_);
        k_gemm3<3><<<dim3(F_/256, M_/256, 1), 512, 0, stream>>>(xin, wcl + WC_U, gbuf, gbuf, D_, D_, F_);
        k_gemm3<0><<<dim3(D_/256, M_/256, 2), 512, 0, stream>>>(gbuf, wcl + WC_D, pR4_0, nullptr, F_/2, F_, D_);

        // down combine + residual + next-input norm (ln1[1] for l=0, final lnf for l=1)
        if (l == 0)
            k_combnorm<1><<<M_, 256, 0, stream>>>(h, pR4_0, pR4_1, ln1 + D_, xin);
        else
            k_combnorm<0><<<M_, 256, 0, stream>>>(h, pR4_0, pR4_1, lnf, hn);
    }

    k_pool1<<<dim3(D_/256, B_, 8), 256, 0, stream>>>(hn, amask, part, cntp);
    k_pool2<<<(B_*D_)/256, 256, 0, stream>>>(part, cntp, (float*)d_out);
}